// Round 5
// baseline (589.052 us; speedup 1.0000x reference)
//
#include <hip/hip_runtime.h>
#include <math.h>

#define N_NODES 50000
#define N_EDGES 800000
#define D 128
#define NH 8
#define EPS 1e-5f
#define QSCALE 0.08838834764831845f  // 128^-0.5

// ---------------------------------------------------------------------------
// CSR build: zero -> histogram -> scan -> fill
// ---------------------------------------------------------------------------
__global__ void k_zero(int* __restrict__ cnt) {
    int i = blockIdx.x * blockDim.x + threadIdx.x;
    if (i < N_NODES) cnt[i] = 0;
}

__global__ void k_hist(const int* __restrict__ dst, int* __restrict__ cnt) {
    int e = blockIdx.x * blockDim.x + threadIdx.x;
    if (e < N_EDGES) atomicAdd(&cnt[dst[e]], 1);
}

#define SCAN_T 1024
#define SCAN_CH ((N_NODES + SCAN_T - 1) / SCAN_T)
__global__ void k_scan(const int* __restrict__ cnt, int* __restrict__ row_start,
                       int* __restrict__ ptrs) {
    __shared__ int ts[SCAN_T];
    const int tid = threadIdx.x;
    const int base = tid * SCAN_CH;
    int local = 0;
    #pragma unroll 4
    for (int i = 0; i < SCAN_CH; i++) {
        int idx = base + i;
        if (idx < N_NODES) local += cnt[idx];
    }
    ts[tid] = local;
    __syncthreads();
    // Hillis-Steele inclusive scan (read / barrier / write / barrier)
    for (int off = 1; off < SCAN_T; off <<= 1) {
        int v = (tid >= off) ? ts[tid - off] : 0;
        __syncthreads();
        ts[tid] += v;
        __syncthreads();
    }
    int run = (tid == 0) ? 0 : ts[tid - 1];
    for (int i = 0; i < SCAN_CH; i++) {
        int idx = base + i;
        if (idx < N_NODES) {
            int c = cnt[idx];          // read BEFORE any write (no-alias safe)
            row_start[idx] = run;
            ptrs[idx] = run;
            run += c;
        }
    }
    if (tid == SCAN_T - 1) row_start[N_NODES] = run;  // == N_EDGES
}

__global__ void k_fill(const int* __restrict__ src, const int* __restrict__ dst,
                       int* __restrict__ ptrs, int* __restrict__ ssrc,
                       int* __restrict__ eidx) {
    int e = blockIdx.x * blockDim.x + threadIdx.x;
    if (e < N_EDGES) {
        int d = dst[e];
        int pos = atomicAdd(&ptrs[d], 1);
        ssrc[pos] = src[e];
        eidx[pos] = e;
    }
}

// ---------------------------------------------------------------------------
// K1: LayerNorm + QKV projection.
// 256 threads, 32 nodes/block. xs[32][132]=16.9KB + ws[96][130]=49.9KB
// = 66.8KB -> 2 blocks/CU. ws read as float2 @ pitch 130:
// bank = (2r + 2k + j) % 32 -> 2 lanes/bank = free (m136).
// ---------------------------------------------------------------------------
__launch_bounds__(256)
__global__ void k_ln_qkv(const float* __restrict__ nf, const float* __restrict__ gamma,
                         const float* __restrict__ beta, const float* __restrict__ Wqkv,
                         const float* __restrict__ bqkv,
                         float* __restrict__ qb, float* __restrict__ kb,
                         float* __restrict__ vb) {
    __shared__ float xs[32][132];
    __shared__ float ws[96][130];
    const int tid = threadIdx.x;
    const int n0 = blockIdx.x * 32;

    // ---- LayerNorm: 8 threads/node, register-resident ----
    {
        const int node = tid >> 3, seg = tid & 7;
        const int gnode = n0 + node;
        float4 xr[4];
        if (gnode < N_NODES) {
            const float* row = nf + (size_t)gnode * D + seg * 16;
            #pragma unroll
            for (int j = 0; j < 4; j++) xr[j] = *(const float4*)(row + j * 4);
        } else {
            #pragma unroll
            for (int j = 0; j < 4; j++) xr[j] = make_float4(0.f, 0.f, 0.f, 0.f);
        }
        float s = 0.f, ss = 0.f;
        #pragma unroll
        for (int j = 0; j < 4; j++) {
            s  += xr[j].x + xr[j].y + xr[j].z + xr[j].w;
            ss += xr[j].x * xr[j].x + xr[j].y * xr[j].y +
                  xr[j].z * xr[j].z + xr[j].w * xr[j].w;
        }
        s += __shfl_xor(s, 1); ss += __shfl_xor(ss, 1);
        s += __shfl_xor(s, 2); ss += __shfl_xor(ss, 2);
        s += __shfl_xor(s, 4); ss += __shfl_xor(ss, 4);
        float mu = s * (1.f / 128.f);
        float var = ss * (1.f / 128.f) - mu * mu;
        float rstd = rsqrtf(var + EPS);
        #pragma unroll
        for (int j = 0; j < 4; j++) {
            float4 g  = *(const float4*)(gamma + seg * 16 + j * 4);
            float4 bt = *(const float4*)(beta  + seg * 16 + j * 4);
            float4 o;
            o.x = (xr[j].x - mu) * rstd * g.x + bt.x;
            o.y = (xr[j].y - mu) * rstd * g.y + bt.y;
            o.z = (xr[j].z - mu) * rstd * g.z + bt.z;
            o.w = (xr[j].w - mu) * rstd * g.w + bt.w;
            *(float4*)&xs[node][seg * 16 + j * 4] = o;
        }
    }
    __syncthreads();

    const int tc = tid & 31, tn = tid >> 5;   // tn in [0,8): nodes tn*4..tn*4+3

    for (int ct = 0; ct < 4; ct++) {
        if (ct) __syncthreads();              // prev reads done before restage
        for (int i = tid; i < 96 * 32; i += 256) {
            int r = i >> 5, off = (i & 31) << 2;
            float4 w = *(const float4*)(Wqkv + (size_t)(ct * 96 + r) * D + off);
            *(float2*)&ws[r][off]     = make_float2(w.x, w.y);
            *(float2*)&ws[r][off + 2] = make_float2(w.z, w.w);
        }
        __syncthreads();

        float acc[4][3];
        #pragma unroll
        for (int a = 0; a < 4; a++)
            #pragma unroll
            for (int b = 0; b < 3; b++) acc[a][b] = 0.f;

        #pragma unroll 2
        for (int k4 = 0; k4 < 32; k4++) {
            float2 wa[3], wb[3];
            #pragma unroll
            for (int b = 0; b < 3; b++) {
                wa[b] = *(const float2*)&ws[tc + 32 * b][k4 * 4];
                wb[b] = *(const float2*)&ws[tc + 32 * b][k4 * 4 + 2];
            }
            #pragma unroll
            for (int a = 0; a < 4; a++) {
                float4 xv = *(const float4*)&xs[tn * 4 + a][k4 * 4];  // broadcast
                #pragma unroll
                for (int b = 0; b < 3; b++) {
                    acc[a][b] += xv.x * wa[b].x + xv.y * wa[b].y +
                                 xv.z * wb[b].x + xv.w * wb[b].y;
                }
            }
        }

        #pragma unroll
        for (int b = 0; b < 3; b++) {
            int c = ct * 96 + tc + 32 * b;    // whole 32-range within one of q/k/v
            float bias = bqkv[c];
            #pragma unroll
            for (int a = 0; a < 4; a++) {
                int node = n0 + tn * 4 + a;
                if (node >= N_NODES) continue;
                float val = acc[a][b] + bias;
                if (c < 128)      qb[(size_t)node * D + c]         = val * QSCALE;
                else if (c < 256) kb[(size_t)node * D + (c - 128)] = val;
                else              vb[(size_t)node * D + (c - 256)] = val;
            }
        }
    }
}

// ---------------------------------------------------------------------------
// K_gather: fused logits + online softmax + weighted-V aggregation.
// One wave per node. Lane l owns dims (2l,2l+1) -> head h = l>>3 (uniform
// per 8-lane group). K-row register-resident; q/v gathered per edge as
// float2 (one coalesced 512B tx per row); 3x shfl_xor head reduce;
// flash-style online rescale. No atomics; agg written exactly once.
// ---------------------------------------------------------------------------
__launch_bounds__(256, 4)
__global__ void k_gather(const float* __restrict__ qb, const float* __restrict__ kb,
                         const float* __restrict__ vb, const float* __restrict__ dist,
                         const float* __restrict__ path,
                         const int* __restrict__ row_start, const int* __restrict__ ssrc,
                         const int* __restrict__ eidx, float* __restrict__ agg) {
    const int node = blockIdx.x * 4 + (threadIdx.x >> 6);
    if (node >= N_NODES) return;
    const int lane = threadIdx.x & 63;
    const int h = lane >> 3;
    const int beg = row_start[node], end = row_start[node + 1];

    const float2 kv = *(const float2*)(kb + (size_t)node * D + 2 * lane);
    float m = -INFINITY, sden = 0.f, ax = 0.f, ay = 0.f;

    int i = beg;
    for (; i + 2 <= end; i += 2) {          // 2-deep pipeline: batch the loads
        int sA = ssrc[i],  sB = ssrc[i + 1];
        int eA = eidx[i],  eB = eidx[i + 1];
        float2 qA = *(const float2*)(qb + (size_t)sA * D + 2 * lane);
        float2 qB = *(const float2*)(qb + (size_t)sB * D + 2 * lane);
        float2 vA = *(const float2*)(vb + (size_t)sA * D + 2 * lane);
        float2 vB = *(const float2*)(vb + (size_t)sB * D + 2 * lane);
        float dpA = dist[eA * 8 + h] + path[eA * 8 + h];
        float dpB = dist[eB * 8 + h] + path[eB * 8 + h];
        float pA = qA.x * kv.x + qA.y * kv.y;
        float pB = qB.x * kv.x + qB.y * kv.y;
        pA += __shfl_xor(pA, 1); pA += __shfl_xor(pA, 2); pA += __shfl_xor(pA, 4);
        pB += __shfl_xor(pB, 1); pB += __shfl_xor(pB, 2); pB += __shfl_xor(pB, 4);
        pA += dpA; pB += dpB;

        float mn = fmaxf(m, pA);
        float c  = __expf(m - mn);
        float w  = __expf(pA - mn);
        sden = sden * c + w;
        ax = ax * c + w * vA.x;
        ay = ay * c + w * vA.y;
        m = mn;

        mn = fmaxf(m, pB);
        c  = __expf(m - mn);
        w  = __expf(pB - mn);
        sden = sden * c + w;
        ax = ax * c + w * vB.x;
        ay = ay * c + w * vB.y;
        m = mn;
    }
    if (i < end) {                           // tail edge
        int sA = ssrc[i];
        int eA = eidx[i];
        float2 qA = *(const float2*)(qb + (size_t)sA * D + 2 * lane);
        float2 vA = *(const float2*)(vb + (size_t)sA * D + 2 * lane);
        float dpA = dist[eA * 8 + h] + path[eA * 8 + h];
        float pA = qA.x * kv.x + qA.y * kv.y;
        pA += __shfl_xor(pA, 1); pA += __shfl_xor(pA, 2); pA += __shfl_xor(pA, 4);
        pA += dpA;
        float mn = fmaxf(m, pA);
        float c  = __expf(m - mn);
        float w  = __expf(pA - mn);
        sden = sden * c + w;
        ax = ax * c + w * vA.x;
        ay = ay * c + w * vA.y;
    }

    float2 r = make_float2(0.f, 0.f);
    if (end > beg) {
        float inv = 1.f / sden;
        r = make_float2(ax * inv, ay * inv);
    }
    *(float2*)(agg + (size_t)node * D + 2 * lane) = r;
}

// ---------------------------------------------------------------------------
// K5: out = node_feature + agg @ W_out.T + b_out
// 64 nodes/block, 2 col-tiles of 64. as[64][132]+ws[64][130] = 67KB
// -> 2 blocks/CU. Conflict-free float2 W reads as in K1.
// ---------------------------------------------------------------------------
__launch_bounds__(256)
__global__ void k_out(const float* __restrict__ agg, const float* __restrict__ Wout,
                      const float* __restrict__ bout, const float* __restrict__ nf,
                      float* __restrict__ out) {
    __shared__ float as_[64][132];
    __shared__ float ws[64][130];
    const int tid = threadIdx.x;
    const int n0 = blockIdx.x * 64;

    for (int i = tid; i < 64 * 32; i += 256) {
        int node = i >> 5, off = (i & 31) << 2;
        float4 w = make_float4(0.f, 0.f, 0.f, 0.f);
        if (n0 + node < N_NODES)
            w = *(const float4*)(agg + (size_t)(n0 + node) * D + off);
        *(float4*)&as_[node][off] = w;
    }

    const int tc = tid & 31, tn = tid >> 5;   // nodes tn*8..tn*8+7

    for (int ct = 0; ct < 2; ct++) {
        if (ct) __syncthreads();
        for (int i = tid; i < 64 * 32; i += 256) {
            int r = i >> 5, off = (i & 31) << 2;
            float4 w = *(const float4*)(Wout + (size_t)(ct * 64 + r) * D + off);
            *(float2*)&ws[r][off]     = make_float2(w.x, w.y);
            *(float2*)&ws[r][off + 2] = make_float2(w.z, w.w);
        }
        __syncthreads();   // also covers as_ staging on ct==0

        float acc[8][2];
        #pragma unroll
        for (int a = 0; a < 8; a++)
            #pragma unroll
            for (int b = 0; b < 2; b++) acc[a][b] = 0.f;

        #pragma unroll 2
        for (int k4 = 0; k4 < 32; k4++) {
            float2 wa[2], wb[2];
            #pragma unroll
            for (int b = 0; b < 2; b++) {
                wa[b] = *(const float2*)&ws[tc + 32 * b][k4 * 4];
                wb[b] = *(const float2*)&ws[tc + 32 * b][k4 * 4 + 2];
            }
            #pragma unroll
            for (int a = 0; a < 8; a++) {
                float4 xv = *(const float4*)&as_[tn * 8 + a][k4 * 4];  // broadcast
                #pragma unroll
                for (int b = 0; b < 2; b++) {
                    acc[a][b] += xv.x * wa[b].x + xv.y * wa[b].y +
                                 xv.z * wb[b].x + xv.w * wb[b].y;
                }
            }
        }

        #pragma unroll
        for (int b = 0; b < 2; b++) {
            int c = ct * 64 + tc + 32 * b;
            float bias = bout[c];
            #pragma unroll
            for (int a = 0; a < 8; a++) {
                int node = n0 + tn * 8 + a;
                if (node >= N_NODES) continue;
                out[(size_t)node * D + c] = nf[(size_t)node * D + c] + bias + acc[a][b];
            }
        }
    }
}

// ---------------------------------------------------------------------------
// launch
// ---------------------------------------------------------------------------
extern "C" void kernel_launch(void* const* d_in, const int* in_sizes, int n_in,
                              void* d_out, int out_size, void* d_ws, size_t ws_size,
                              hipStream_t stream) {
    const float* nf    = (const float*)d_in[0];
    const float* dist  = (const float*)d_in[1];
    const float* path  = (const float*)d_in[2];
    const float* gamma = (const float*)d_in[3];
    const float* beta  = (const float*)d_in[4];
    const float* Wqkv  = (const float*)d_in[5];
    const float* bqkv  = (const float*)d_in[6];
    const float* Wout  = (const float*)d_in[7];
    const float* bout  = (const float*)d_in[8];
    const int*   src   = (const int*)d_in[9];
    const int*   dst   = (const int*)d_in[10];
    float* out = (float*)d_out;

    // workspace layout: 4 x N*128 floats + CSR ints (~109.5 MB total)
    float* qb  = (float*)d_ws;
    float* kb  = qb + (size_t)N_NODES * D;
    float* vb  = kb + (size_t)N_NODES * D;
    float* agg = vb + (size_t)N_NODES * D;
    int* ssrc      = (int*)(agg + (size_t)N_NODES * D);   // N_EDGES
    int* eidx      = ssrc + N_EDGES;                      // N_EDGES
    int* cnt       = eidx + N_EDGES;                      // N_NODES
    int* ptrs      = cnt + N_NODES;                       // N_NODES
    int* row_start = ptrs + N_NODES;                      // N_NODES + 1

    (void)in_sizes; (void)n_in; (void)out_size; (void)ws_size;

    hipLaunchKernelGGL(k_zero, dim3((N_NODES + 255) / 256), dim3(256), 0, stream, cnt);
    hipLaunchKernelGGL(k_hist, dim3((N_EDGES + 255) / 256), dim3(256), 0, stream,
                       dst, cnt);
    hipLaunchKernelGGL(k_scan, dim3(1), dim3(SCAN_T), 0, stream,
                       cnt, row_start, ptrs);
    hipLaunchKernelGGL(k_fill, dim3((N_EDGES + 255) / 256), dim3(256), 0, stream,
                       src, dst, ptrs, ssrc, eidx);

    hipLaunchKernelGGL(k_ln_qkv, dim3((N_NODES + 31) / 32), dim3(256), 0, stream,
                       nf, gamma, beta, Wqkv, bqkv, qb, kb, vb);

    hipLaunchKernelGGL(k_gather, dim3((N_NODES + 3) / 4), dim3(256), 0, stream,
                       qb, kb, vb, dist, path, row_start, ssrc, eidx, agg);

    hipLaunchKernelGGL(k_out, dim3((N_NODES + 63) / 64), dim3(256), 0, stream,
                       agg, Wout, bout, nf, out);
}

// Round 6
// 586.980 us; speedup vs baseline: 1.0035x; 1.0035x over previous
//
#include <hip/hip_runtime.h>
#include <math.h>

#define N_NODES 50000
#define N_EDGES 800000
#define D 128
#define NH 8
#define EPS 1e-5f
#define QSCALE 0.08838834764831845f  // 128^-0.5

// ---------------------------------------------------------------------------
// CSR build: zero -> histogram -> scan -> fill
// ---------------------------------------------------------------------------
__global__ void k_zero(int* __restrict__ cnt) {
    int i = blockIdx.x * blockDim.x + threadIdx.x;
    if (i < N_NODES) cnt[i] = 0;
}

__global__ void k_hist(const int* __restrict__ dst, int* __restrict__ cnt) {
    int e = blockIdx.x * blockDim.x + threadIdx.x;
    if (e < N_EDGES) atomicAdd(&cnt[dst[e]], 1);
}

#define SCAN_T 1024
#define SCAN_CH ((N_NODES + SCAN_T - 1) / SCAN_T)
__global__ void k_scan(const int* __restrict__ cnt, int* __restrict__ row_start,
                       int* __restrict__ ptrs) {
    __shared__ int ts[SCAN_T];
    const int tid = threadIdx.x;
    const int base = tid * SCAN_CH;
    int local = 0;
    #pragma unroll 4
    for (int i = 0; i < SCAN_CH; i++) {
        int idx = base + i;
        if (idx < N_NODES) local += cnt[idx];
    }
    ts[tid] = local;
    __syncthreads();
    // Hillis-Steele inclusive scan (read / barrier / write / barrier)
    for (int off = 1; off < SCAN_T; off <<= 1) {
        int v = (tid >= off) ? ts[tid - off] : 0;
        __syncthreads();
        ts[tid] += v;
        __syncthreads();
    }
    int run = (tid == 0) ? 0 : ts[tid - 1];
    for (int i = 0; i < SCAN_CH; i++) {
        int idx = base + i;
        if (idx < N_NODES) {
            int c = cnt[idx];          // read BEFORE any write (no-alias safe)
            row_start[idx] = run;
            ptrs[idx] = run;
            run += c;
        }
    }
    if (tid == SCAN_T - 1) row_start[N_NODES] = run;  // == N_EDGES
}

__global__ void k_fill(const int* __restrict__ src, const int* __restrict__ dst,
                       int* __restrict__ ptrs, int* __restrict__ ssrc,
                       int* __restrict__ eidx) {
    int e = blockIdx.x * blockDim.x + threadIdx.x;
    if (e < N_EDGES) {
        int d = dst[e];
        int pos = atomicAdd(&ptrs[d], 1);
        ssrc[pos] = src[e];
        eidx[pos] = e;
    }
}

// ---------------------------------------------------------------------------
// K1: LayerNorm + QKV projection.
// 256 threads, 32 nodes/block. xs[32][132]=16.9KB + ws[96][130]=49.9KB
// = 66.8KB -> 2 blocks/CU. ws read as float2 @ pitch 130:
// bank = (2r + 2k + j) % 32 -> 2 lanes/bank = free (m136).
// ---------------------------------------------------------------------------
__launch_bounds__(256)
__global__ void k_ln_qkv(const float* __restrict__ nf, const float* __restrict__ gamma,
                         const float* __restrict__ beta, const float* __restrict__ Wqkv,
                         const float* __restrict__ bqkv,
                         float* __restrict__ qb, float* __restrict__ kb,
                         float* __restrict__ vb) {
    __shared__ float xs[32][132];
    __shared__ float ws[96][130];
    const int tid = threadIdx.x;
    const int n0 = blockIdx.x * 32;

    // ---- LayerNorm: 8 threads/node, register-resident ----
    {
        const int node = tid >> 3, seg = tid & 7;
        const int gnode = n0 + node;
        float4 xr[4];
        if (gnode < N_NODES) {
            const float* row = nf + (size_t)gnode * D + seg * 16;
            #pragma unroll
            for (int j = 0; j < 4; j++) xr[j] = *(const float4*)(row + j * 4);
        } else {
            #pragma unroll
            for (int j = 0; j < 4; j++) xr[j] = make_float4(0.f, 0.f, 0.f, 0.f);
        }
        float s = 0.f, ss = 0.f;
        #pragma unroll
        for (int j = 0; j < 4; j++) {
            s  += xr[j].x + xr[j].y + xr[j].z + xr[j].w;
            ss += xr[j].x * xr[j].x + xr[j].y * xr[j].y +
                  xr[j].z * xr[j].z + xr[j].w * xr[j].w;
        }
        s += __shfl_xor(s, 1); ss += __shfl_xor(ss, 1);
        s += __shfl_xor(s, 2); ss += __shfl_xor(ss, 2);
        s += __shfl_xor(s, 4); ss += __shfl_xor(ss, 4);
        float mu = s * (1.f / 128.f);
        float var = ss * (1.f / 128.f) - mu * mu;
        float rstd = rsqrtf(var + EPS);
        #pragma unroll
        for (int j = 0; j < 4; j++) {
            float4 g  = *(const float4*)(gamma + seg * 16 + j * 4);
            float4 bt = *(const float4*)(beta  + seg * 16 + j * 4);
            float4 o;
            o.x = (xr[j].x - mu) * rstd * g.x + bt.x;
            o.y = (xr[j].y - mu) * rstd * g.y + bt.y;
            o.z = (xr[j].z - mu) * rstd * g.z + bt.z;
            o.w = (xr[j].w - mu) * rstd * g.w + bt.w;
            *(float4*)&xs[node][seg * 16 + j * 4] = o;
        }
    }
    __syncthreads();

    const int tc = tid & 31, tn = tid >> 5;   // tn in [0,8): nodes tn*4..tn*4+3

    for (int ct = 0; ct < 4; ct++) {
        if (ct) __syncthreads();              // prev reads done before restage
        for (int i = tid; i < 96 * 32; i += 256) {
            int r = i >> 5, off = (i & 31) << 2;
            float4 w = *(const float4*)(Wqkv + (size_t)(ct * 96 + r) * D + off);
            *(float2*)&ws[r][off]     = make_float2(w.x, w.y);
            *(float2*)&ws[r][off + 2] = make_float2(w.z, w.w);
        }
        __syncthreads();

        float acc[4][3];
        #pragma unroll
        for (int a = 0; a < 4; a++)
            #pragma unroll
            for (int b = 0; b < 3; b++) acc[a][b] = 0.f;

        #pragma unroll 2
        for (int k4 = 0; k4 < 32; k4++) {
            float2 wa[3], wb[3];
            #pragma unroll
            for (int b = 0; b < 3; b++) {
                wa[b] = *(const float2*)&ws[tc + 32 * b][k4 * 4];
                wb[b] = *(const float2*)&ws[tc + 32 * b][k4 * 4 + 2];
            }
            #pragma unroll
            for (int a = 0; a < 4; a++) {
                float4 xv = *(const float4*)&xs[tn * 4 + a][k4 * 4];  // broadcast
                #pragma unroll
                for (int b = 0; b < 3; b++) {
                    acc[a][b] += xv.x * wa[b].x + xv.y * wa[b].y +
                                 xv.z * wb[b].x + xv.w * wb[b].y;
                }
            }
        }

        #pragma unroll
        for (int b = 0; b < 3; b++) {
            int c = ct * 96 + tc + 32 * b;    // whole 32-range within one of q/k/v
            float bias = bqkv[c];
            #pragma unroll
            for (int a = 0; a < 4; a++) {
                int node = n0 + tn * 4 + a;
                if (node >= N_NODES) continue;
                float val = acc[a][b] + bias;
                if (c < 128)      qb[(size_t)node * D + c]         = val * QSCALE;
                else if (c < 256) kb[(size_t)node * D + (c - 128)] = val;
                else              vb[(size_t)node * D + (c - 256)] = val;
            }
        }
    }
}

// ---------------------------------------------------------------------------
// K_gather: fused logits + online softmax + weighted-V aggregation.
// One wave per node. Lane l owns dims (2l,2l+1) -> head h = l>>3 (uniform
// per 8-lane group). K-row register-resident; q/v gathered per edge as
// float2 (one coalesced 512B tx per row); 3x shfl_xor head reduce;
// flash-style online rescale. No atomics; agg written exactly once.
// ---------------------------------------------------------------------------
__launch_bounds__(256, 4)
__global__ void k_gather(const float* __restrict__ qb, const float* __restrict__ kb,
                         const float* __restrict__ vb, const float* __restrict__ dist,
                         const float* __restrict__ path,
                         const int* __restrict__ row_start, const int* __restrict__ ssrc,
                         const int* __restrict__ eidx, float* __restrict__ agg) {
    const int node = blockIdx.x * 4 + (threadIdx.x >> 6);
    if (node >= N_NODES) return;
    const int lane = threadIdx.x & 63;
    const int h = lane >> 3;
    const int beg = row_start[node], end = row_start[node + 1];

    const float2 kv = *(const float2*)(kb + (size_t)node * D + 2 * lane);
    float m = -INFINITY, sden = 0.f, ax = 0.f, ay = 0.f;

    int i = beg;
    for (; i + 2 <= end; i += 2) {          // 2-deep pipeline: batch the loads
        int sA = ssrc[i],  sB = ssrc[i + 1];
        int eA = eidx[i],  eB = eidx[i + 1];
        float2 qA = *(const float2*)(qb + (size_t)sA * D + 2 * lane);
        float2 qB = *(const float2*)(qb + (size_t)sB * D + 2 * lane);
        float2 vA = *(const float2*)(vb + (size_t)sA * D + 2 * lane);
        float2 vB = *(const float2*)(vb + (size_t)sB * D + 2 * lane);
        float dpA = dist[eA * 8 + h] + path[eA * 8 + h];
        float dpB = dist[eB * 8 + h] + path[eB * 8 + h];
        float pA = qA.x * kv.x + qA.y * kv.y;
        float pB = qB.x * kv.x + qB.y * kv.y;
        pA += __shfl_xor(pA, 1); pA += __shfl_xor(pA, 2); pA += __shfl_xor(pA, 4);
        pB += __shfl_xor(pB, 1); pB += __shfl_xor(pB, 2); pB += __shfl_xor(pB, 4);
        pA += dpA; pB += dpB;

        float mn = fmaxf(m, pA);
        float c  = __expf(m - mn);
        float w  = __expf(pA - mn);
        sden = sden * c + w;
        ax = ax * c + w * vA.x;
        ay = ay * c + w * vA.y;
        m = mn;

        mn = fmaxf(m, pB);
        c  = __expf(m - mn);
        w  = __expf(pB - mn);
        sden = sden * c + w;
        ax = ax * c + w * vB.x;
        ay = ay * c + w * vB.y;
        m = mn;
    }
    if (i < end) {                           // tail edge
        int sA = ssrc[i];
        int eA = eidx[i];
        float2 qA = *(const float2*)(qb + (size_t)sA * D + 2 * lane);
        float2 vA = *(const float2*)(vb + (size_t)sA * D + 2 * lane);
        float dpA = dist[eA * 8 + h] + path[eA * 8 + h];
        float pA = qA.x * kv.x + qA.y * kv.y;
        pA += __shfl_xor(pA, 1); pA += __shfl_xor(pA, 2); pA += __shfl_xor(pA, 4);
        pA += dpA;
        float mn = fmaxf(m, pA);
        float c  = __expf(m - mn);
        float w  = __expf(pA - mn);
        sden = sden * c + w;
        ax = ax * c + w * vA.x;
        ay = ay * c + w * vA.y;
    }

    float2 r = make_float2(0.f, 0.f);
    if (end > beg) {
        float inv = 1.f / sden;
        r = make_float2(ax * inv, ay * inv);
    }
    *(float2*)(agg + (size_t)node * D + 2 * lane) = r;
}

// ---------------------------------------------------------------------------
// K5: out = node_feature + agg @ W_out.T + b_out
// 64 nodes/block, 2 col-tiles of 64. as[64][132]+ws[64][130] = 67KB
// -> 2 blocks/CU. Conflict-free float2 W reads as in K1.
// ---------------------------------------------------------------------------
__launch_bounds__(256)
__global__ void k_out(const float* __restrict__ agg, const float* __restrict__ Wout,
                      const float* __restrict__ bout, const float* __restrict__ nf,
                      float* __restrict__ out) {
    __shared__ float as_[64][132];
    __shared__ float ws[64][130];
    const int tid = threadIdx.x;
    const int n0 = blockIdx.x * 64;

    for (int i = tid; i < 64 * 32; i += 256) {
        int node = i >> 5, off = (i & 31) << 2;
        float4 w = make_float4(0.f, 0.f, 0.f, 0.f);
        if (n0 + node < N_NODES)
            w = *(const float4*)(agg + (size_t)(n0 + node) * D + off);
        *(float4*)&as_[node][off] = w;
    }

    const int tc = tid & 31, tn = tid >> 5;   // nodes tn*8..tn*8+7

    for (int ct = 0; ct < 2; ct++) {
        if (ct) __syncthreads();
        for (int i = tid; i < 64 * 32; i += 256) {
            int r = i >> 5, off = (i & 31) << 2;
            float4 w = *(const float4*)(Wout + (size_t)(ct * 64 + r) * D + off);
            *(float2*)&ws[r][off]     = make_float2(w.x, w.y);
            *(float2*)&ws[r][off + 2] = make_float2(w.z, w.w);
        }
        __syncthreads();   // also covers as_ staging on ct==0

        float acc[8][2];
        #pragma unroll
        for (int a = 0; a < 8; a++)
            #pragma unroll
            for (int b = 0; b < 2; b++) acc[a][b] = 0.f;

        #pragma unroll 2
        for (int k4 = 0; k4 < 32; k4++) {
            float2 wa[2], wb[2];
            #pragma unroll
            for (int b = 0; b < 2; b++) {
                wa[b] = *(const float2*)&ws[tc + 32 * b][k4 * 4];
                wb[b] = *(const float2*)&ws[tc + 32 * b][k4 * 4 + 2];
            }
            #pragma unroll
            for (int a = 0; a < 8; a++) {
                float4 xv = *(const float4*)&as_[tn * 8 + a][k4 * 4];  // broadcast
                #pragma unroll
                for (int b = 0; b < 2; b++) {
                    acc[a][b] += xv.x * wa[b].x + xv.y * wa[b].y +
                                 xv.z * wb[b].x + xv.w * wb[b].y;
                }
            }
        }

        #pragma unroll
        for (int b = 0; b < 2; b++) {
            int c = ct * 64 + tc + 32 * b;
            float bias = bout[c];
            #pragma unroll
            for (int a = 0; a < 8; a++) {
                int node = n0 + tn * 8 + a;
                if (node >= N_NODES) continue;
                out[(size_t)node * D + c] = nf[(size_t)node * D + c] + bias + acc[a][b];
            }
        }
    }
}

// ---------------------------------------------------------------------------
// launch
// ---------------------------------------------------------------------------
extern "C" void kernel_launch(void* const* d_in, const int* in_sizes, int n_in,
                              void* d_out, int out_size, void* d_ws, size_t ws_size,
                              hipStream_t stream) {
    const float* nf    = (const float*)d_in[0];
    const float* dist  = (const float*)d_in[1];
    const float* path  = (const float*)d_in[2];
    const float* gamma = (const float*)d_in[3];
    const float* beta  = (const float*)d_in[4];
    const float* Wqkv  = (const float*)d_in[5];
    const float* bqkv  = (const float*)d_in[6];
    const float* Wout  = (const float*)d_in[7];
    const float* bout  = (const float*)d_in[8];
    const int*   src   = (const int*)d_in[9];
    const int*   dst   = (const int*)d_in[10];
    float* out = (float*)d_out;

    // workspace layout: 4 x N*128 floats + CSR ints (~109.5 MB total)
    float* qb  = (float*)d_ws;
    float* kb  = qb + (size_t)N_NODES * D;
    float* vb  = kb + (size_t)N_NODES * D;
    float* agg = vb + (size_t)N_NODES * D;
    int* ssrc      = (int*)(agg + (size_t)N_NODES * D);   // N_EDGES
    int* eidx      = ssrc + N_EDGES;                      // N_EDGES
    int* cnt       = eidx + N_EDGES;                      // N_NODES
    int* ptrs      = cnt + N_NODES;                       // N_NODES
    int* row_start = ptrs + N_NODES;                      // N_NODES + 1

    (void)in_sizes; (void)n_in; (void)out_size; (void)ws_size;

    hipLaunchKernelGGL(k_zero, dim3((N_NODES + 255) / 256), dim3(256), 0, stream, cnt);
    hipLaunchKernelGGL(k_hist, dim3((N_EDGES + 255) / 256), dim3(256), 0, stream,
                       dst, cnt);
    hipLaunchKernelGGL(k_scan, dim3(1), dim3(SCAN_T), 0, stream,
                       cnt, row_start, ptrs);
    hipLaunchKernelGGL(k_fill, dim3((N_EDGES + 255) / 256), dim3(256), 0, stream,
                       src, dst, ptrs, ssrc, eidx);

    hipLaunchKernelGGL(k_ln_qkv, dim3((N_NODES + 31) / 32), dim3(256), 0, stream,
                       nf, gamma, beta, Wqkv, bqkv, qb, kb, vb);

    hipLaunchKernelGGL(k_gather, dim3((N_NODES + 3) / 4), dim3(256), 0, stream,
                       qb, kb, vb, dist, path, row_start, ssrc, eidx, agg);

    hipLaunchKernelGGL(k_out, dim3((N_NODES + 63) / 64), dim3(256), 0, stream,
                       agg, Wout, bout, nf, out);
}

// Round 7
// 586.063 us; speedup vs baseline: 1.0051x; 1.0016x over previous
//
#include <hip/hip_runtime.h>
#include <math.h>

#define N_NODES 50000
#define N_EDGES 800000
#define D 128
#define NH 8
#define EPS 1e-5f
#define QSCALE 0.08838834764831845f  // 128^-0.5

// ---------------------------------------------------------------------------
// CSR build: zero -> histogram -> scan -> fill
// ---------------------------------------------------------------------------
__global__ void k_zero(int* __restrict__ cnt) {
    int i = blockIdx.x * blockDim.x + threadIdx.x;
    if (i < N_NODES) cnt[i] = 0;
}

__global__ void k_hist(const int* __restrict__ dst, int* __restrict__ cnt) {
    int e = blockIdx.x * blockDim.x + threadIdx.x;
    if (e < N_EDGES) atomicAdd(&cnt[dst[e]], 1);
}

#define SCAN_T 1024
#define SCAN_CH ((N_NODES + SCAN_T - 1) / SCAN_T)
__global__ void k_scan(const int* __restrict__ cnt, int* __restrict__ row_start,
                       int* __restrict__ ptrs) {
    __shared__ int ts[SCAN_T];
    const int tid = threadIdx.x;
    const int base = tid * SCAN_CH;
    int local = 0;
    #pragma unroll 4
    for (int i = 0; i < SCAN_CH; i++) {
        int idx = base + i;
        if (idx < N_NODES) local += cnt[idx];
    }
    ts[tid] = local;
    __syncthreads();
    // Hillis-Steele inclusive scan (read / barrier / write / barrier)
    for (int off = 1; off < SCAN_T; off <<= 1) {
        int v = (tid >= off) ? ts[tid - off] : 0;
        __syncthreads();
        ts[tid] += v;
        __syncthreads();
    }
    int run = (tid == 0) ? 0 : ts[tid - 1];
    for (int i = 0; i < SCAN_CH; i++) {
        int idx = base + i;
        if (idx < N_NODES) {
            int c = cnt[idx];          // read BEFORE any write (no-alias safe)
            row_start[idx] = run;
            ptrs[idx] = run;
            run += c;
        }
    }
    if (tid == SCAN_T - 1) row_start[N_NODES] = run;  // == N_EDGES
}

__global__ void k_fill(const int* __restrict__ src, const int* __restrict__ dst,
                       int* __restrict__ ptrs, int* __restrict__ ssrc,
                       int* __restrict__ eidx) {
    int e = blockIdx.x * blockDim.x + threadIdx.x;
    if (e < N_EDGES) {
        int d = dst[e];
        int pos = atomicAdd(&ptrs[d], 1);
        ssrc[pos] = src[e];
        eidx[pos] = e;
    }
}

// ---------------------------------------------------------------------------
// K1: LayerNorm + QKV projection.
// 256 threads, 32 nodes/block. xs[32][132]=16.9KB + ws[96][130]=49.9KB
// = 66.8KB -> 2 blocks/CU. ws read as float2 @ pitch 130:
// bank = (2r + 2k + j) % 32 -> 2 lanes/bank = free (m136).
// ---------------------------------------------------------------------------
__launch_bounds__(256)
__global__ void k_ln_qkv(const float* __restrict__ nf, const float* __restrict__ gamma,
                         const float* __restrict__ beta, const float* __restrict__ Wqkv,
                         const float* __restrict__ bqkv,
                         float* __restrict__ qb, float* __restrict__ kb,
                         float* __restrict__ vb) {
    __shared__ float xs[32][132];
    __shared__ float ws[96][130];
    const int tid = threadIdx.x;
    const int n0 = blockIdx.x * 32;

    // ---- LayerNorm: 8 threads/node, register-resident ----
    {
        const int node = tid >> 3, seg = tid & 7;
        const int gnode = n0 + node;
        float4 xr[4];
        if (gnode < N_NODES) {
            const float* row = nf + (size_t)gnode * D + seg * 16;
            #pragma unroll
            for (int j = 0; j < 4; j++) xr[j] = *(const float4*)(row + j * 4);
        } else {
            #pragma unroll
            for (int j = 0; j < 4; j++) xr[j] = make_float4(0.f, 0.f, 0.f, 0.f);
        }
        float s = 0.f, ss = 0.f;
        #pragma unroll
        for (int j = 0; j < 4; j++) {
            s  += xr[j].x + xr[j].y + xr[j].z + xr[j].w;
            ss += xr[j].x * xr[j].x + xr[j].y * xr[j].y +
                  xr[j].z * xr[j].z + xr[j].w * xr[j].w;
        }
        s += __shfl_xor(s, 1); ss += __shfl_xor(ss, 1);
        s += __shfl_xor(s, 2); ss += __shfl_xor(ss, 2);
        s += __shfl_xor(s, 4); ss += __shfl_xor(ss, 4);
        float mu = s * (1.f / 128.f);
        float var = ss * (1.f / 128.f) - mu * mu;
        float rstd = rsqrtf(var + EPS);
        #pragma unroll
        for (int j = 0; j < 4; j++) {
            float4 g  = *(const float4*)(gamma + seg * 16 + j * 4);
            float4 bt = *(const float4*)(beta  + seg * 16 + j * 4);
            float4 o;
            o.x = (xr[j].x - mu) * rstd * g.x + bt.x;
            o.y = (xr[j].y - mu) * rstd * g.y + bt.y;
            o.z = (xr[j].z - mu) * rstd * g.z + bt.z;
            o.w = (xr[j].w - mu) * rstd * g.w + bt.w;
            *(float4*)&xs[node][seg * 16 + j * 4] = o;
        }
    }
    __syncthreads();

    const int tc = tid & 31, tn = tid >> 5;   // tn in [0,8): nodes tn*4..tn*4+3

    for (int ct = 0; ct < 4; ct++) {
        if (ct) __syncthreads();              // prev reads done before restage
        for (int i = tid; i < 96 * 32; i += 256) {
            int r = i >> 5, off = (i & 31) << 2;
            float4 w = *(const float4*)(Wqkv + (size_t)(ct * 96 + r) * D + off);
            *(float2*)&ws[r][off]     = make_float2(w.x, w.y);
            *(float2*)&ws[r][off + 2] = make_float2(w.z, w.w);
        }
        __syncthreads();

        float acc[4][3];
        #pragma unroll
        for (int a = 0; a < 4; a++)
            #pragma unroll
            for (int b = 0; b < 3; b++) acc[a][b] = 0.f;

        #pragma unroll 2
        for (int k4 = 0; k4 < 32; k4++) {
            float2 wa[3], wb[3];
            #pragma unroll
            for (int b = 0; b < 3; b++) {
                wa[b] = *(const float2*)&ws[tc + 32 * b][k4 * 4];
                wb[b] = *(const float2*)&ws[tc + 32 * b][k4 * 4 + 2];
            }
            #pragma unroll
            for (int a = 0; a < 4; a++) {
                float4 xv = *(const float4*)&xs[tn * 4 + a][k4 * 4];  // broadcast
                #pragma unroll
                for (int b = 0; b < 3; b++) {
                    acc[a][b] += xv.x * wa[b].x + xv.y * wa[b].y +
                                 xv.z * wb[b].x + xv.w * wb[b].y;
                }
            }
        }

        #pragma unroll
        for (int b = 0; b < 3; b++) {
            int c = ct * 96 + tc + 32 * b;    // whole 32-range within one of q/k/v
            float bias = bqkv[c];
            #pragma unroll
            for (int a = 0; a < 4; a++) {
                int node = n0 + tn * 4 + a;
                if (node >= N_NODES) continue;
                float val = acc[a][b] + bias;
                if (c < 128)      qb[(size_t)node * D + c]         = val * QSCALE;
                else if (c < 256) kb[(size_t)node * D + (c - 128)] = val;
                else              vb[(size_t)node * D + (c - 256)] = val;
            }
        }
    }
}

// ---------------------------------------------------------------------------
// K_gather: fused logits + online softmax + weighted-V aggregation.
// One wave per node. Lane l owns dims (2l,2l+1) -> head h = l>>3 (uniform
// per 8-lane group). K-row register-resident; q/v gathered per edge as
// float2 (one coalesced 512B tx per row); 3x shfl_xor head reduce;
// flash-style online rescale. No atomics; agg written exactly once.
// ---------------------------------------------------------------------------
__launch_bounds__(256, 4)
__global__ void k_gather(const float* __restrict__ qb, const float* __restrict__ kb,
                         const float* __restrict__ vb, const float* __restrict__ dist,
                         const float* __restrict__ path,
                         const int* __restrict__ row_start, const int* __restrict__ ssrc,
                         const int* __restrict__ eidx, float* __restrict__ agg) {
    const int node = blockIdx.x * 4 + (threadIdx.x >> 6);
    if (node >= N_NODES) return;
    const int lane = threadIdx.x & 63;
    const int h = lane >> 3;
    const int beg = row_start[node], end = row_start[node + 1];

    const float2 kv = *(const float2*)(kb + (size_t)node * D + 2 * lane);
    float m = -INFINITY, sden = 0.f, ax = 0.f, ay = 0.f;

    int i = beg;
    for (; i + 2 <= end; i += 2) {          // 2-deep pipeline: batch the loads
        int sA = ssrc[i],  sB = ssrc[i + 1];
        int eA = eidx[i],  eB = eidx[i + 1];
        float2 qA = *(const float2*)(qb + (size_t)sA * D + 2 * lane);
        float2 qB = *(const float2*)(qb + (size_t)sB * D + 2 * lane);
        float2 vA = *(const float2*)(vb + (size_t)sA * D + 2 * lane);
        float2 vB = *(const float2*)(vb + (size_t)sB * D + 2 * lane);
        float dpA = dist[eA * 8 + h] + path[eA * 8 + h];
        float dpB = dist[eB * 8 + h] + path[eB * 8 + h];
        float pA = qA.x * kv.x + qA.y * kv.y;
        float pB = qB.x * kv.x + qB.y * kv.y;
        pA += __shfl_xor(pA, 1); pA += __shfl_xor(pA, 2); pA += __shfl_xor(pA, 4);
        pB += __shfl_xor(pB, 1); pB += __shfl_xor(pB, 2); pB += __shfl_xor(pB, 4);
        pA += dpA; pB += dpB;

        float mn = fmaxf(m, pA);
        float c  = __expf(m - mn);
        float w  = __expf(pA - mn);
        sden = sden * c + w;
        ax = ax * c + w * vA.x;
        ay = ay * c + w * vA.y;
        m = mn;

        mn = fmaxf(m, pB);
        c  = __expf(m - mn);
        w  = __expf(pB - mn);
        sden = sden * c + w;
        ax = ax * c + w * vB.x;
        ay = ay * c + w * vB.y;
        m = mn;
    }
    if (i < end) {                           // tail edge
        int sA = ssrc[i];
        int eA = eidx[i];
        float2 qA = *(const float2*)(qb + (size_t)sA * D + 2 * lane);
        float2 vA = *(const float2*)(vb + (size_t)sA * D + 2 * lane);
        float dpA = dist[eA * 8 + h] + path[eA * 8 + h];
        float pA = qA.x * kv.x + qA.y * kv.y;
        pA += __shfl_xor(pA, 1); pA += __shfl_xor(pA, 2); pA += __shfl_xor(pA, 4);
        pA += dpA;
        float mn = fmaxf(m, pA);
        float c  = __expf(m - mn);
        float w  = __expf(pA - mn);
        sden = sden * c + w;
        ax = ax * c + w * vA.x;
        ay = ay * c + w * vA.y;
    }

    float2 r = make_float2(0.f, 0.f);
    if (end > beg) {
        float inv = 1.f / sden;
        r = make_float2(ax * inv, ay * inv);
    }
    *(float2*)(agg + (size_t)node * D + 2 * lane) = r;
}

// ---------------------------------------------------------------------------
// K5: out = node_feature + agg @ W_out.T + b_out
// 64 nodes/block, 2 col-tiles of 64. as[64][132]+ws[64][130] = 67KB
// -> 2 blocks/CU. Conflict-free float2 W reads as in K1.
// ---------------------------------------------------------------------------
__launch_bounds__(256)
__global__ void k_out(const float* __restrict__ agg, const float* __restrict__ Wout,
                      const float* __restrict__ bout, const float* __restrict__ nf,
                      float* __restrict__ out) {
    __shared__ float as_[64][132];
    __shared__ float ws[64][130];
    const int tid = threadIdx.x;
    const int n0 = blockIdx.x * 64;

    for (int i = tid; i < 64 * 32; i += 256) {
        int node = i >> 5, off = (i & 31) << 2;
        float4 w = make_float4(0.f, 0.f, 0.f, 0.f);
        if (n0 + node < N_NODES)
            w = *(const float4*)(agg + (size_t)(n0 + node) * D + off);
        *(float4*)&as_[node][off] = w;
    }

    const int tc = tid & 31, tn = tid >> 5;   // nodes tn*8..tn*8+7

    for (int ct = 0; ct < 2; ct++) {
        if (ct) __syncthreads();
        for (int i = tid; i < 64 * 32; i += 256) {
            int r = i >> 5, off = (i & 31) << 2;
            float4 w = *(const float4*)(Wout + (size_t)(ct * 64 + r) * D + off);
            *(float2*)&ws[r][off]     = make_float2(w.x, w.y);
            *(float2*)&ws[r][off + 2] = make_float2(w.z, w.w);
        }
        __syncthreads();   // also covers as_ staging on ct==0

        float acc[8][2];
        #pragma unroll
        for (int a = 0; a < 8; a++)
            #pragma unroll
            for (int b = 0; b < 2; b++) acc[a][b] = 0.f;

        #pragma unroll 2
        for (int k4 = 0; k4 < 32; k4++) {
            float2 wa[2], wb[2];
            #pragma unroll
            for (int b = 0; b < 2; b++) {
                wa[b] = *(const float2*)&ws[tc + 32 * b][k4 * 4];
                wb[b] = *(const float2*)&ws[tc + 32 * b][k4 * 4 + 2];
            }
            #pragma unroll
            for (int a = 0; a < 8; a++) {
                float4 xv = *(const float4*)&as_[tn * 8 + a][k4 * 4];  // broadcast
                #pragma unroll
                for (int b = 0; b < 2; b++) {
                    acc[a][b] += xv.x * wa[b].x + xv.y * wa[b].y +
                                 xv.z * wb[b].x + xv.w * wb[b].y;
                }
            }
        }

        #pragma unroll
        for (int b = 0; b < 2; b++) {
            int c = ct * 64 + tc + 32 * b;
            float bias = bout[c];
            #pragma unroll
            for (int a = 0; a < 8; a++) {
                int node = n0 + tn * 8 + a;
                if (node >= N_NODES) continue;
                out[(size_t)node * D + c] = nf[(size_t)node * D + c] + bias + acc[a][b];
            }
        }
    }
}

// ---------------------------------------------------------------------------
// launch
// ---------------------------------------------------------------------------
extern "C" void kernel_launch(void* const* d_in, const int* in_sizes, int n_in,
                              void* d_out, int out_size, void* d_ws, size_t ws_size,
                              hipStream_t stream) {
    const float* nf    = (const float*)d_in[0];
    const float* dist  = (const float*)d_in[1];
    const float* path  = (const float*)d_in[2];
    const float* gamma = (const float*)d_in[3];
    const float* beta  = (const float*)d_in[4];
    const float* Wqkv  = (const float*)d_in[5];
    const float* bqkv  = (const float*)d_in[6];
    const float* Wout  = (const float*)d_in[7];
    const float* bout  = (const float*)d_in[8];
    const int*   src   = (const int*)d_in[9];
    const int*   dst   = (const int*)d_in[10];
    float* out = (float*)d_out;

    // workspace layout: 4 x N*128 floats + CSR ints (~109.5 MB total)
    float* qb  = (float*)d_ws;
    float* kb  = qb + (size_t)N_NODES * D;
    float* vb  = kb + (size_t)N_NODES * D;
    float* agg = vb + (size_t)N_NODES * D;
    int* ssrc      = (int*)(agg + (size_t)N_NODES * D);   // N_EDGES
    int* eidx      = ssrc + N_EDGES;                      // N_EDGES
    int* cnt       = eidx + N_EDGES;                      // N_NODES
    int* ptrs      = cnt + N_NODES;                       // N_NODES
    int* row_start = ptrs + N_NODES;                      // N_NODES + 1

    (void)in_sizes; (void)n_in; (void)out_size; (void)ws_size;

    hipLaunchKernelGGL(k_zero, dim3((N_NODES + 255) / 256), dim3(256), 0, stream, cnt);
    hipLaunchKernelGGL(k_hist, dim3((N_EDGES + 255) / 256), dim3(256), 0, stream,
                       dst, cnt);
    hipLaunchKernelGGL(k_scan, dim3(1), dim3(SCAN_T), 0, stream,
                       cnt, row_start, ptrs);
    hipLaunchKernelGGL(k_fill, dim3((N_EDGES + 255) / 256), dim3(256), 0, stream,
                       src, dst, ptrs, ssrc, eidx);

    hipLaunchKernelGGL(k_ln_qkv, dim3((N_NODES + 31) / 32), dim3(256), 0, stream,
                       nf, gamma, beta, Wqkv, bqkv, qb, kb, vb);

    hipLaunchKernelGGL(k_gather, dim3((N_NODES + 3) / 4), dim3(256), 0, stream,
                       qb, kb, vb, dist, path, row_start, ssrc, eidx, agg);

    hipLaunchKernelGGL(k_out, dim3((N_NODES + 63) / 64), dim3(256), 0, stream,
                       agg, Wout, bout, nf, out);
}

// Round 8
// 493.585 us; speedup vs baseline: 1.1934x; 1.1874x over previous
//
#include <hip/hip_runtime.h>
#include <math.h>

#define N_NODES 50000
#define N_EDGES 800000
#define D 128
#define NH 8
#define EPS 1e-5f
#define QSCALE 0.08838834764831845f  // 128^-0.5

typedef __attribute__((ext_vector_type(8))) short short8;
typedef __attribute__((ext_vector_type(4))) float f32x4;

// bf16 round-to-nearest-even helpers (bit-pattern in ushort)
__device__ __forceinline__ unsigned short f2bf_rne(float f) {
    unsigned int u = __float_as_uint(f);
    u += 0x7fff + ((u >> 16) & 1);
    return (unsigned short)(u >> 16);
}
__device__ __forceinline__ float bf2f(unsigned short h) {
    return __uint_as_float(((unsigned int)h) << 16);
}

// ---------------------------------------------------------------------------
// CSR build: zero -> histogram -> scan -> fill  (unchanged)
// ---------------------------------------------------------------------------
__global__ void k_zero(int* __restrict__ cnt) {
    int i = blockIdx.x * blockDim.x + threadIdx.x;
    if (i < N_NODES) cnt[i] = 0;
}

__global__ void k_hist(const int* __restrict__ dst, int* __restrict__ cnt) {
    int e = blockIdx.x * blockDim.x + threadIdx.x;
    if (e < N_EDGES) atomicAdd(&cnt[dst[e]], 1);
}

#define SCAN_T 1024
#define SCAN_CH ((N_NODES + SCAN_T - 1) / SCAN_T)
__global__ void k_scan(const int* __restrict__ cnt, int* __restrict__ row_start,
                       int* __restrict__ ptrs) {
    __shared__ int ts[SCAN_T];
    const int tid = threadIdx.x;
    const int base = tid * SCAN_CH;
    int local = 0;
    #pragma unroll 4
    for (int i = 0; i < SCAN_CH; i++) {
        int idx = base + i;
        if (idx < N_NODES) local += cnt[idx];
    }
    ts[tid] = local;
    __syncthreads();
    for (int off = 1; off < SCAN_T; off <<= 1) {
        int v = (tid >= off) ? ts[tid - off] : 0;
        __syncthreads();
        ts[tid] += v;
        __syncthreads();
    }
    int run = (tid == 0) ? 0 : ts[tid - 1];
    for (int i = 0; i < SCAN_CH; i++) {
        int idx = base + i;
        if (idx < N_NODES) {
            int c = cnt[idx];
            row_start[idx] = run;
            ptrs[idx] = run;
            run += c;
        }
    }
    if (tid == SCAN_T - 1) row_start[N_NODES] = run;
}

__global__ void k_fill(const int* __restrict__ src, const int* __restrict__ dst,
                       int* __restrict__ ptrs, int* __restrict__ ssrc,
                       int* __restrict__ eidx) {
    int e = blockIdx.x * blockDim.x + threadIdx.x;
    if (e < N_EDGES) {
        int d = dst[e];
        int pos = atomicAdd(&ptrs[d], 1);
        ssrc[pos] = src[e];
        eidx[pos] = e;
    }
}

// ---------------------------------------------------------------------------
// K_prep: split W_qkv and W_out into bf16 hi/lo (for bf16x3 fp32-accurate MFMA)
// ---------------------------------------------------------------------------
__global__ void k_prep(const float* __restrict__ Wqkv, const float* __restrict__ Wout,
                       unsigned short* __restrict__ wq_hi, unsigned short* __restrict__ wq_lo,
                       unsigned short* __restrict__ wo_hi, unsigned short* __restrict__ wo_lo) {
    int i = blockIdx.x * blockDim.x + threadIdx.x;
    if (i < 384 * 128) {
        float w = Wqkv[i];
        unsigned short h = f2bf_rne(w);
        wq_hi[i] = h;
        wq_lo[i] = f2bf_rne(w - bf2f(h));
    }
    if (i < 128 * 128) {
        float w = Wout[i];
        unsigned short h = f2bf_rne(w);
        wo_hi[i] = h;
        wo_lo[i] = f2bf_rne(w - bf2f(h));
    }
}

// ---------------------------------------------------------------------------
// K1: LayerNorm + QKV projection via MFMA bf16x3 (fp32-equivalent).
// No LDS, no barriers. Wave = 16 nodes; block = 4 waves = 64 nodes.
// A-frag layout (16x16x32): lane l holds A[l&15][(l>>4)*8+j] -> the LN is
// computed by exactly those lanes, fully in registers.
// C/D: col=lane&15, row=(lane>>4)*4+reg  [m89-verified].
// ---------------------------------------------------------------------------
__launch_bounds__(256)
__global__ void k_ln_qkv(const float* __restrict__ nf, const float* __restrict__ gamma,
                         const float* __restrict__ beta,
                         const unsigned short* __restrict__ w_hi,
                         const unsigned short* __restrict__ w_lo,
                         const float* __restrict__ bqkv,
                         float* __restrict__ qb, float* __restrict__ kb,
                         float* __restrict__ vb) {
    const int lane  = threadIdx.x & 63;
    const int wv    = threadIdx.x >> 6;
    const int nbase = blockIdx.x * 64 + wv * 16;
    const int mrow  = lane & 15;   // A-row (input node) AND B-col (W row)
    const int kg    = lane >> 4;   // k-group: k = t*32 + kg*8 + j

    // ---- load this lane's 32 k-elements of node nbase+mrow ----
    int gn = nbase + mrow;
    if (gn >= N_NODES) gn = N_NODES - 1;           // clamp; stores are guarded
    const float* xrow = nf + (size_t)gn * D + kg * 8;
    float4 xa[4], xb[4];
    #pragma unroll
    for (int t = 0; t < 4; t++) {
        xa[t] = *(const float4*)(xrow + t * 32);
        xb[t] = *(const float4*)(xrow + t * 32 + 4);
    }

    // ---- LN stats: reduce over the 4 lanes sharing this node (xor 16,32) ----
    float s = 0.f, ss = 0.f;
    #pragma unroll
    for (int t = 0; t < 4; t++) {
        s  += xa[t].x + xa[t].y + xa[t].z + xa[t].w
            + xb[t].x + xb[t].y + xb[t].z + xb[t].w;
        ss += xa[t].x * xa[t].x + xa[t].y * xa[t].y + xa[t].z * xa[t].z + xa[t].w * xa[t].w
            + xb[t].x * xb[t].x + xb[t].y * xb[t].y + xb[t].z * xb[t].z + xb[t].w * xb[t].w;
    }
    s += __shfl_xor(s, 16); ss += __shfl_xor(ss, 16);
    s += __shfl_xor(s, 32); ss += __shfl_xor(ss, 32);
    float mu   = s * (1.f / 128.f);
    float var  = ss * (1.f / 128.f) - mu * mu;
    float rstd = rsqrtf(var + EPS);

    // ---- normalize + hi/lo split + pack A-fragments ----
    short8 ahi[4], alo[4];
    #pragma unroll
    for (int t = 0; t < 4; t++) {
        const float* gp = gamma + kg * 8 + t * 32;
        const float* bp = beta  + kg * 8 + t * 32;
        float4 g0 = *(const float4*)gp,       g1 = *(const float4*)(gp + 4);
        float4 b0 = *(const float4*)bp,       b1 = *(const float4*)(bp + 4);
        float xn[8];
        xn[0] = (xa[t].x - mu) * rstd * g0.x + b0.x;
        xn[1] = (xa[t].y - mu) * rstd * g0.y + b0.y;
        xn[2] = (xa[t].z - mu) * rstd * g0.z + b0.z;
        xn[3] = (xa[t].w - mu) * rstd * g0.w + b0.w;
        xn[4] = (xb[t].x - mu) * rstd * g1.x + b1.x;
        xn[5] = (xb[t].y - mu) * rstd * g1.y + b1.y;
        xn[6] = (xb[t].z - mu) * rstd * g1.z + b1.z;
        xn[7] = (xb[t].w - mu) * rstd * g1.w + b1.w;
        #pragma unroll
        for (int j = 0; j < 8; j++) {
            unsigned short h = f2bf_rne(xn[j]);
            ahi[t][j] = (short)h;
            alo[t][j] = (short)f2bf_rne(xn[j] - bf2f(h));
        }
    }

    // ---- 24 N-tiles of 16 cols: D = Xhi*Whi + Xlo*Whi + Xhi*Wlo ----
    for (int nt = 0; nt < 24; nt++) {
        const unsigned short* wrh = w_hi + ((size_t)(nt * 16 + mrow)) * D + kg * 8;
        const unsigned short* wrl = w_lo + ((size_t)(nt * 16 + mrow)) * D + kg * 8;
        f32x4 acc0 = {0.f, 0.f, 0.f, 0.f};
        f32x4 acc1 = {0.f, 0.f, 0.f, 0.f};
        #pragma unroll
        for (int t = 0; t < 4; t++) {
            short8 bh = *(const short8*)(wrh + t * 32);
            short8 bl = *(const short8*)(wrl + t * 32);
            acc0 = __builtin_amdgcn_mfma_f32_16x16x32_bf16(ahi[t], bh, acc0, 0, 0, 0);
            acc1 = __builtin_amdgcn_mfma_f32_16x16x32_bf16(alo[t], bh, acc1, 0, 0, 0);
            acc0 = __builtin_amdgcn_mfma_f32_16x16x32_bf16(ahi[t], bl, acc0, 0, 0, 0);
        }

        const int col = nt * 16 + (lane & 15);
        float bias = bqkv[col];
        float* dstp; int cc; float scale;
        if (col < 128)      { dstp = qb; cc = col;       scale = QSCALE; }
        else if (col < 256) { dstp = kb; cc = col - 128; scale = 1.f; }
        else                { dstp = vb; cc = col - 256; scale = 1.f; }
        #pragma unroll
        for (int r = 0; r < 4; r++) {
            int node = nbase + kg * 4 + r;   // D-row = (lane>>4)*4 + r
            if (node < N_NODES)
                dstp[(size_t)node * D + cc] = (acc0[r] + acc1[r] + bias) * scale;
        }
    }
}

// ---------------------------------------------------------------------------
// K_gather: fused logits + online softmax + weighted-V aggregation (unchanged)
// ---------------------------------------------------------------------------
__launch_bounds__(256, 4)
__global__ void k_gather(const float* __restrict__ qb, const float* __restrict__ kb,
                         const float* __restrict__ vb, const float* __restrict__ dist,
                         const float* __restrict__ path,
                         const int* __restrict__ row_start, const int* __restrict__ ssrc,
                         const int* __restrict__ eidx, float* __restrict__ agg) {
    const int node = blockIdx.x * 4 + (threadIdx.x >> 6);
    if (node >= N_NODES) return;
    const int lane = threadIdx.x & 63;
    const int h = lane >> 3;
    const int beg = row_start[node], end = row_start[node + 1];

    const float2 kv = *(const float2*)(kb + (size_t)node * D + 2 * lane);
    float m = -INFINITY, sden = 0.f, ax = 0.f, ay = 0.f;

    int i = beg;
    for (; i + 2 <= end; i += 2) {
        int sA = ssrc[i],  sB = ssrc[i + 1];
        int eA = eidx[i],  eB = eidx[i + 1];
        float2 qA = *(const float2*)(qb + (size_t)sA * D + 2 * lane);
        float2 qB = *(const float2*)(qb + (size_t)sB * D + 2 * lane);
        float2 vA = *(const float2*)(vb + (size_t)sA * D + 2 * lane);
        float2 vB = *(const float2*)(vb + (size_t)sB * D + 2 * lane);
        float dpA = dist[eA * 8 + h] + path[eA * 8 + h];
        float dpB = dist[eB * 8 + h] + path[eB * 8 + h];
        float pA = qA.x * kv.x + qA.y * kv.y;
        float pB = qB.x * kv.x + qB.y * kv.y;
        pA += __shfl_xor(pA, 1); pA += __shfl_xor(pA, 2); pA += __shfl_xor(pA, 4);
        pB += __shfl_xor(pB, 1); pB += __shfl_xor(pB, 2); pB += __shfl_xor(pB, 4);
        pA += dpA; pB += dpB;

        float mn = fmaxf(m, pA);
        float c  = __expf(m - mn);
        float w  = __expf(pA - mn);
        sden = sden * c + w;
        ax = ax * c + w * vA.x;
        ay = ay * c + w * vA.y;
        m = mn;

        mn = fmaxf(m, pB);
        c  = __expf(m - mn);
        w  = __expf(pB - mn);
        sden = sden * c + w;
        ax = ax * c + w * vB.x;
        ay = ay * c + w * vB.y;
        m = mn;
    }
    if (i < end) {
        int sA = ssrc[i];
        int eA = eidx[i];
        float2 qA = *(const float2*)(qb + (size_t)sA * D + 2 * lane);
        float2 vA = *(const float2*)(vb + (size_t)sA * D + 2 * lane);
        float dpA = dist[eA * 8 + h] + path[eA * 8 + h];
        float pA = qA.x * kv.x + qA.y * kv.y;
        pA += __shfl_xor(pA, 1); pA += __shfl_xor(pA, 2); pA += __shfl_xor(pA, 4);
        pA += dpA;
        float mn = fmaxf(m, pA);
        float c  = __expf(m - mn);
        float w  = __expf(pA - mn);
        sden = sden * c + w;
        ax = ax * c + w * vA.x;
        ay = ay * c + w * vA.y;
    }

    float2 r = make_float2(0.f, 0.f);
    if (end > beg) {
        float inv = 1.f / sden;
        r = make_float2(ax * inv, ay * inv);
    }
    *(float2*)(agg + (size_t)node * D + 2 * lane) = r;
}

// ---------------------------------------------------------------------------
// K5: out = node_feature + agg @ W_out.T + b_out, via MFMA bf16x3.
// Same fragment scheme as K1, no LDS/barriers.
// ---------------------------------------------------------------------------
__launch_bounds__(256)
__global__ void k_out(const float* __restrict__ agg,
                      const unsigned short* __restrict__ w_hi,
                      const unsigned short* __restrict__ w_lo,
                      const float* __restrict__ bout, const float* __restrict__ nf,
                      float* __restrict__ out) {
    const int lane  = threadIdx.x & 63;
    const int wv    = threadIdx.x >> 6;
    const int nbase = blockIdx.x * 64 + wv * 16;
    const int mrow  = lane & 15;
    const int kg    = lane >> 4;

    int gn = nbase + mrow;
    if (gn >= N_NODES) gn = N_NODES - 1;
    const float* arow = agg + (size_t)gn * D + kg * 8;

    short8 ahi[4], alo[4];
    #pragma unroll
    for (int t = 0; t < 4; t++) {
        float4 x0 = *(const float4*)(arow + t * 32);
        float4 x1 = *(const float4*)(arow + t * 32 + 4);
        float xn[8] = {x0.x, x0.y, x0.z, x0.w, x1.x, x1.y, x1.z, x1.w};
        #pragma unroll
        for (int j = 0; j < 8; j++) {
            unsigned short h = f2bf_rne(xn[j]);
            ahi[t][j] = (short)h;
            alo[t][j] = (short)f2bf_rne(xn[j] - bf2f(h));
        }
    }

    for (int nt = 0; nt < 8; nt++) {
        const unsigned short* wrh = w_hi + ((size_t)(nt * 16 + mrow)) * D + kg * 8;
        const unsigned short* wrl = w_lo + ((size_t)(nt * 16 + mrow)) * D + kg * 8;
        f32x4 acc0 = {0.f, 0.f, 0.f, 0.f};
        f32x4 acc1 = {0.f, 0.f, 0.f, 0.f};
        #pragma unroll
        for (int t = 0; t < 4; t++) {
            short8 bh = *(const short8*)(wrh + t * 32);
            short8 bl = *(const short8*)(wrl + t * 32);
            acc0 = __builtin_amdgcn_mfma_f32_16x16x32_bf16(ahi[t], bh, acc0, 0, 0, 0);
            acc1 = __builtin_amdgcn_mfma_f32_16x16x32_bf16(alo[t], bh, acc1, 0, 0, 0);
            acc0 = __builtin_amdgcn_mfma_f32_16x16x32_bf16(ahi[t], bl, acc0, 0, 0, 0);
        }

        const int col = nt * 16 + (lane & 15);
        float bias = bout[col];
        #pragma unroll
        for (int r = 0; r < 4; r++) {
            int node = nbase + kg * 4 + r;
            if (node < N_NODES)
                out[(size_t)node * D + col] =
                    nf[(size_t)node * D + col] + bias + acc0[r] + acc1[r];
        }
    }
}

// ---------------------------------------------------------------------------
// launch
// ---------------------------------------------------------------------------
extern "C" void kernel_launch(void* const* d_in, const int* in_sizes, int n_in,
                              void* d_out, int out_size, void* d_ws, size_t ws_size,
                              hipStream_t stream) {
    const float* nf    = (const float*)d_in[0];
    const float* dist  = (const float*)d_in[1];
    const float* path  = (const float*)d_in[2];
    const float* gamma = (const float*)d_in[3];
    const float* beta  = (const float*)d_in[4];
    const float* Wqkv  = (const float*)d_in[5];
    const float* bqkv  = (const float*)d_in[6];
    const float* Wout  = (const float*)d_in[7];
    const float* bout  = (const float*)d_in[8];
    const int*   src   = (const int*)d_in[9];
    const int*   dst   = (const int*)d_in[10];
    float* out = (float*)d_out;

    // workspace layout: 4 x N*128 floats, CSR ints, then bf16 hi/lo weights
    float* qb  = (float*)d_ws;
    float* kb  = qb + (size_t)N_NODES * D;
    float* vb  = kb + (size_t)N_NODES * D;
    float* agg = vb + (size_t)N_NODES * D;
    int* ssrc      = (int*)(agg + (size_t)N_NODES * D);   // N_EDGES
    int* eidx      = ssrc + N_EDGES;                      // N_EDGES
    int* cnt       = eidx + N_EDGES;                      // N_NODES
    int* ptrs      = cnt + N_NODES;                       // N_NODES
    int* row_start = ptrs + N_NODES;                      // N_NODES + 1
    uintptr_t p = (uintptr_t)(row_start + N_NODES + 1);
    p = (p + 15) & ~(uintptr_t)15;                        // 16B align for short8
    unsigned short* wq_hi = (unsigned short*)p;           // 384*128
    unsigned short* wq_lo = wq_hi + 384 * 128;
    unsigned short* wo_hi = wq_lo + 384 * 128;            // 128*128
    unsigned short* wo_lo = wo_hi + 128 * 128;

    (void)in_sizes; (void)n_in; (void)out_size; (void)ws_size;

    hipLaunchKernelGGL(k_prep, dim3(192), dim3(256), 0, stream,
                       Wqkv, Wout, wq_hi, wq_lo, wo_hi, wo_lo);

    hipLaunchKernelGGL(k_zero, dim3((N_NODES + 255) / 256), dim3(256), 0, stream, cnt);
    hipLaunchKernelGGL(k_hist, dim3((N_EDGES + 255) / 256), dim3(256), 0, stream,
                       dst, cnt);
    hipLaunchKernelGGL(k_scan, dim3(1), dim3(SCAN_T), 0, stream,
                       cnt, row_start, ptrs);
    hipLaunchKernelGGL(k_fill, dim3((N_EDGES + 255) / 256), dim3(256), 0, stream,
                       src, dst, ptrs, ssrc, eidx);

    hipLaunchKernelGGL(k_ln_qkv, dim3((N_NODES + 63) / 64), dim3(256), 0, stream,
                       nf, gamma, beta, wq_hi, wq_lo, bqkv, qb, kb, vb);

    hipLaunchKernelGGL(k_gather, dim3((N_NODES + 3) / 4), dim3(256), 0, stream,
                       qb, kb, vb, dist, path, row_start, ssrc, eidx, agg);

    hipLaunchKernelGGL(k_out, dim3((N_NODES + 63) / 64), dim3(256), 0, stream,
                       agg, wo_hi, wo_lo, bout, nf, out);
}

// Round 9
// 423.350 us; speedup vs baseline: 1.3914x; 1.1659x over previous
//
#include <hip/hip_runtime.h>
#include <math.h>

#define N_NODES 50000
#define N_EDGES 800000
#define D 128
#define NH 8
#define EPS 1e-5f
#define QSCALE 0.08838834764831845f  // 128^-0.5

typedef __attribute__((ext_vector_type(8))) short short8;
typedef __attribute__((ext_vector_type(4))) float f32x4;

// bf16 round-to-nearest-even helpers (bit-pattern in ushort)
__device__ __forceinline__ unsigned short f2bf_rne(float f) {
    unsigned int u = __float_as_uint(f);
    u += 0x7fff + ((u >> 16) & 1);
    return (unsigned short)(u >> 16);
}
__device__ __forceinline__ float bf2f(unsigned short h) {
    return __uint_as_float(((unsigned int)h) << 16);
}
// unpack a uint holding [lo: bf16 a][hi: bf16 b] -> (a, b)
__device__ __forceinline__ float2 bfpair(unsigned int u) {
    return make_float2(__uint_as_float(u << 16),
                       __uint_as_float(u & 0xffff0000u));
}

// ---------------------------------------------------------------------------
// CSR build: zero -> histogram -> scan -> fill (+dp pre-gather)
// ---------------------------------------------------------------------------
__global__ void k_zero(int* __restrict__ cnt) {
    int i = blockIdx.x * blockDim.x + threadIdx.x;
    if (i < N_NODES) cnt[i] = 0;
}

__global__ void k_hist(const int* __restrict__ dst, int* __restrict__ cnt) {
    int e = blockIdx.x * blockDim.x + threadIdx.x;
    if (e < N_EDGES) atomicAdd(&cnt[dst[e]], 1);
}

#define SCAN_T 1024
#define SCAN_CH ((N_NODES + SCAN_T - 1) / SCAN_T)
__global__ void k_scan(const int* __restrict__ cnt, int* __restrict__ row_start,
                       int* __restrict__ ptrs) {
    __shared__ int ts[SCAN_T];
    const int tid = threadIdx.x;
    const int base = tid * SCAN_CH;
    int local = 0;
    #pragma unroll 4
    for (int i = 0; i < SCAN_CH; i++) {
        int idx = base + i;
        if (idx < N_NODES) local += cnt[idx];
    }
    ts[tid] = local;
    __syncthreads();
    for (int off = 1; off < SCAN_T; off <<= 1) {
        int v = (tid >= off) ? ts[tid - off] : 0;
        __syncthreads();
        ts[tid] += v;
        __syncthreads();
    }
    int run = (tid == 0) ? 0 : ts[tid - 1];
    for (int i = 0; i < SCAN_CH; i++) {
        int idx = base + i;
        if (idx < N_NODES) {
            int c = cnt[idx];
            row_start[idx] = run;
            ptrs[idx] = run;
            run += c;
        }
    }
    if (tid == SCAN_T - 1) row_start[N_NODES] = run;
}

// fill: CSR src list + dist/path pre-gathered (summed) into CSR order.
// dist/path reads are fully coalesced (thread e reads e*8..e*8+7);
// dp writes cluster by dst row (consecutive pos within a node).
__global__ void k_fill(const int* __restrict__ src, const int* __restrict__ dst,
                       const float* __restrict__ dist, const float* __restrict__ path,
                       int* __restrict__ ptrs, int* __restrict__ ssrc,
                       float* __restrict__ dp) {
    int e = blockIdx.x * blockDim.x + threadIdx.x;
    if (e < N_EDGES) {
        int d = dst[e];
        int pos = atomicAdd(&ptrs[d], 1);
        ssrc[pos] = src[e];
        #pragma unroll
        for (int h = 0; h < 8; h++)
            dp[(size_t)pos * 8 + h] = dist[(size_t)e * 8 + h] + path[(size_t)e * 8 + h];
    }
}

// ---------------------------------------------------------------------------
// K_prep: split W_qkv and W_out into bf16 hi/lo (for bf16x3 fp32-accurate MFMA)
// ---------------------------------------------------------------------------
__global__ void k_prep(const float* __restrict__ Wqkv, const float* __restrict__ Wout,
                       unsigned short* __restrict__ wq_hi, unsigned short* __restrict__ wq_lo,
                       unsigned short* __restrict__ wo_hi, unsigned short* __restrict__ wo_lo) {
    int i = blockIdx.x * blockDim.x + threadIdx.x;
    if (i < 384 * 128) {
        float w = Wqkv[i];
        unsigned short h = f2bf_rne(w);
        wq_hi[i] = h;
        wq_lo[i] = f2bf_rne(w - bf2f(h));
    }
    if (i < 128 * 128) {
        float w = Wout[i];
        unsigned short h = f2bf_rne(w);
        wo_hi[i] = h;
        wo_lo[i] = f2bf_rne(w - bf2f(h));
    }
}

// ---------------------------------------------------------------------------
// K1: LayerNorm + QKV projection via MFMA bf16x3 (fp32-equivalent).
// q and v are emitted as bf16 into the interleaved qv record:
//   ushort idx(n, pair p, j) : n*256 + p*4 + {0,1}=q pair, {2,3}=v pair
// so k_gather's lane l reads ONE uint2 (q2l,q2l+1,v2l,v2l+1) at n*512+8l bytes.
// k stays fp32 (read once per node, register-resident in k_gather).
// ---------------------------------------------------------------------------
__launch_bounds__(256)
__global__ void k_ln_qkv(const float* __restrict__ nf, const float* __restrict__ gamma,
                         const float* __restrict__ beta,
                         const unsigned short* __restrict__ w_hi,
                         const unsigned short* __restrict__ w_lo,
                         const float* __restrict__ bqkv,
                         unsigned short* __restrict__ qv, float* __restrict__ kb) {
    const int lane  = threadIdx.x & 63;
    const int wv    = threadIdx.x >> 6;
    const int nbase = blockIdx.x * 64 + wv * 16;
    const int mrow  = lane & 15;   // A-row (input node) AND B-col (W row)
    const int kg    = lane >> 4;   // k-group: k = t*32 + kg*8 + j

    int gn = nbase + mrow;
    if (gn >= N_NODES) gn = N_NODES - 1;           // clamp; stores are guarded
    const float* xrow = nf + (size_t)gn * D + kg * 8;
    float4 xa[4], xb[4];
    #pragma unroll
    for (int t = 0; t < 4; t++) {
        xa[t] = *(const float4*)(xrow + t * 32);
        xb[t] = *(const float4*)(xrow + t * 32 + 4);
    }

    // LN stats: reduce over the 4 lanes sharing this node (xor 16,32)
    float s = 0.f, ss = 0.f;
    #pragma unroll
    for (int t = 0; t < 4; t++) {
        s  += xa[t].x + xa[t].y + xa[t].z + xa[t].w
            + xb[t].x + xb[t].y + xb[t].z + xb[t].w;
        ss += xa[t].x * xa[t].x + xa[t].y * xa[t].y + xa[t].z * xa[t].z + xa[t].w * xa[t].w
            + xb[t].x * xb[t].x + xb[t].y * xb[t].y + xb[t].z * xb[t].z + xb[t].w * xb[t].w;
    }
    s += __shfl_xor(s, 16); ss += __shfl_xor(ss, 16);
    s += __shfl_xor(s, 32); ss += __shfl_xor(ss, 32);
    float mu   = s * (1.f / 128.f);
    float var  = ss * (1.f / 128.f) - mu * mu;
    float rstd = rsqrtf(var + EPS);

    // normalize + hi/lo split + pack A-fragments
    short8 ahi[4], alo[4];
    #pragma unroll
    for (int t = 0; t < 4; t++) {
        const float* gp = gamma + kg * 8 + t * 32;
        const float* bp = beta  + kg * 8 + t * 32;
        float4 g0 = *(const float4*)gp, g1 = *(const float4*)(gp + 4);
        float4 b0 = *(const float4*)bp, b1 = *(const float4*)(bp + 4);
        float xn[8];
        xn[0] = (xa[t].x - mu) * rstd * g0.x + b0.x;
        xn[1] = (xa[t].y - mu) * rstd * g0.y + b0.y;
        xn[2] = (xa[t].z - mu) * rstd * g0.z + b0.z;
        xn[3] = (xa[t].w - mu) * rstd * g0.w + b0.w;
        xn[4] = (xb[t].x - mu) * rstd * g1.x + b1.x;
        xn[5] = (xb[t].y - mu) * rstd * g1.y + b1.y;
        xn[6] = (xb[t].z - mu) * rstd * g1.z + b1.z;
        xn[7] = (xb[t].w - mu) * rstd * g1.w + b1.w;
        #pragma unroll
        for (int j = 0; j < 8; j++) {
            unsigned short h = f2bf_rne(xn[j]);
            ahi[t][j] = (short)h;
            alo[t][j] = (short)f2bf_rne(xn[j] - bf2f(h));
        }
    }

    // 24 N-tiles of 16 cols: D = Xhi*Whi + Xlo*Whi + Xhi*Wlo
    for (int nt = 0; nt < 24; nt++) {
        const unsigned short* wrh = w_hi + ((size_t)(nt * 16 + mrow)) * D + kg * 8;
        const unsigned short* wrl = w_lo + ((size_t)(nt * 16 + mrow)) * D + kg * 8;
        f32x4 acc0 = {0.f, 0.f, 0.f, 0.f};
        f32x4 acc1 = {0.f, 0.f, 0.f, 0.f};
        #pragma unroll
        for (int t = 0; t < 4; t++) {
            short8 bh = *(const short8*)(wrh + t * 32);
            short8 bl = *(const short8*)(wrl + t * 32);
            acc0 = __builtin_amdgcn_mfma_f32_16x16x32_bf16(ahi[t], bh, acc0, 0, 0, 0);
            acc1 = __builtin_amdgcn_mfma_f32_16x16x32_bf16(alo[t], bh, acc1, 0, 0, 0);
            acc0 = __builtin_amdgcn_mfma_f32_16x16x32_bf16(ahi[t], bl, acc0, 0, 0, 0);
        }

        const int col = nt * 16 + mrow;
        float bias = bqkv[col];
        #pragma unroll
        for (int r = 0; r < 4; r++) {
            int node = nbase + kg * 4 + r;   // D-row = (lane>>4)*4 + r
            if (node >= N_NODES) continue;
            float val = acc0[r] + acc1[r] + bias;
            if (col < 128) {
                // q, pre-scaled, bf16 into qv
                qv[(size_t)node * 256 + (col >> 1) * 4 + (col & 1)] =
                    f2bf_rne(val * QSCALE);
            } else if (col < 256) {
                kb[(size_t)node * D + (col - 128)] = val;
            } else {
                int cv = col - 256;
                qv[(size_t)node * 256 + (cv >> 1) * 4 + 2 + (cv & 1)] =
                    f2bf_rne(val);
            }
        }
    }
}

// ---------------------------------------------------------------------------
// K_gather: fused logits + online softmax + weighted-V aggregation.
// One wave per node. Lane l owns dims (2l,2l+1); head h = l>>3.
// Per edge: ONE uint2 gather (q-pair + v-pair, 512B/wave coalesced) +
// sequential dp read. No atomics; agg written exactly once.
// ---------------------------------------------------------------------------
__launch_bounds__(256, 4)
__global__ void k_gather(const unsigned short* __restrict__ qv,
                         const float* __restrict__ kb,
                         const float* __restrict__ dp,
                         const int* __restrict__ row_start,
                         const int* __restrict__ ssrc,
                         float* __restrict__ agg) {
    const int node = blockIdx.x * 4 + (threadIdx.x >> 6);
    if (node >= N_NODES) return;
    const int lane = threadIdx.x & 63;
    const int h = lane >> 3;
    const int beg = row_start[node], end = row_start[node + 1];

    const float2 kv = *(const float2*)(kb + (size_t)node * D + 2 * lane);
    float m = -INFINITY, sden = 0.f, ax = 0.f, ay = 0.f;

    int i = beg;
    for (; i + 2 <= end; i += 2) {          // 2-deep: batch the loads
        int sA = ssrc[i], sB = ssrc[i + 1];
        uint2 pa = *(const uint2*)(qv + (size_t)sA * 256 + lane * 4);
        uint2 pb = *(const uint2*)(qv + (size_t)sB * 256 + lane * 4);
        float dpA = dp[(size_t)i * 8 + h];
        float dpB = dp[(size_t)(i + 1) * 8 + h];
        float2 qA = bfpair(pa.x), vA = bfpair(pa.y);
        float2 qB = bfpair(pb.x), vB = bfpair(pb.y);
        float pA = qA.x * kv.x + qA.y * kv.y;
        float pB = qB.x * kv.x + qB.y * kv.y;
        pA += __shfl_xor(pA, 1); pA += __shfl_xor(pA, 2); pA += __shfl_xor(pA, 4);
        pB += __shfl_xor(pB, 1); pB += __shfl_xor(pB, 2); pB += __shfl_xor(pB, 4);
        pA += dpA; pB += dpB;

        float mn = fmaxf(m, pA);
        float c  = __expf(m - mn);
        float w  = __expf(pA - mn);
        sden = sden * c + w;
        ax = ax * c + w * vA.x;
        ay = ay * c + w * vA.y;
        m = mn;

        mn = fmaxf(m, pB);
        c  = __expf(m - mn);
        w  = __expf(pB - mn);
        sden = sden * c + w;
        ax = ax * c + w * vB.x;
        ay = ay * c + w * vB.y;
        m = mn;
    }
    if (i < end) {                           // tail edge
        int sA = ssrc[i];
        uint2 pa = *(const uint2*)(qv + (size_t)sA * 256 + lane * 4);
        float dpA = dp[(size_t)i * 8 + h];
        float2 qA = bfpair(pa.x), vA = bfpair(pa.y);
        float pA = qA.x * kv.x + qA.y * kv.y;
        pA += __shfl_xor(pA, 1); pA += __shfl_xor(pA, 2); pA += __shfl_xor(pA, 4);
        pA += dpA;
        float mn = fmaxf(m, pA);
        float c  = __expf(m - mn);
        float w  = __expf(pA - mn);
        sden = sden * c + w;
        ax = ax * c + w * vA.x;
        ay = ay * c + w * vA.y;
    }

    float2 r = make_float2(0.f, 0.f);
    if (end > beg) {
        float inv = 1.f / sden;
        r = make_float2(ax * inv, ay * inv);
    }
    *(float2*)(agg + (size_t)node * D + 2 * lane) = r;
}

// ---------------------------------------------------------------------------
// K5: out = node_feature + agg @ W_out.T + b_out, via MFMA bf16x3.
// ---------------------------------------------------------------------------
__launch_bounds__(256)
__global__ void k_out(const float* __restrict__ agg,
                      const unsigned short* __restrict__ w_hi,
                      const unsigned short* __restrict__ w_lo,
                      const float* __restrict__ bout, const float* __restrict__ nf,
                      float* __restrict__ out) {
    const int lane  = threadIdx.x & 63;
    const int wv    = threadIdx.x >> 6;
    const int nbase = blockIdx.x * 64 + wv * 16;
    const int mrow  = lane & 15;
    const int kg    = lane >> 4;

    int gn = nbase + mrow;
    if (gn >= N_NODES) gn = N_NODES - 1;
    const float* arow = agg + (size_t)gn * D + kg * 8;

    short8 ahi[4], alo[4];
    #pragma unroll
    for (int t = 0; t < 4; t++) {
        float4 x0 = *(const float4*)(arow + t * 32);
        float4 x1 = *(const float4*)(arow + t * 32 + 4);
        float xn[8] = {x0.x, x0.y, x0.z, x0.w, x1.x, x1.y, x1.z, x1.w};
        #pragma unroll
        for (int j = 0; j < 8; j++) {
            unsigned short h = f2bf_rne(xn[j]);
            ahi[t][j] = (short)h;
            alo[t][j] = (short)f2bf_rne(xn[j] - bf2f(h));
        }
    }

    for (int nt = 0; nt < 8; nt++) {
        const unsigned short* wrh = w_hi + ((size_t)(nt * 16 + mrow)) * D + kg * 8;
        const unsigned short* wrl = w_lo + ((size_t)(nt * 16 + mrow)) * D + kg * 8;
        f32x4 acc0 = {0.f, 0.f, 0.f, 0.f};
        f32x4 acc1 = {0.f, 0.f, 0.f, 0.f};
        #pragma unroll
        for (int t = 0; t < 4; t++) {
            short8 bh = *(const short8*)(wrh + t * 32);
            short8 bl = *(const short8*)(wrl + t * 32);
            acc0 = __builtin_amdgcn_mfma_f32_16x16x32_bf16(ahi[t], bh, acc0, 0, 0, 0);
            acc1 = __builtin_amdgcn_mfma_f32_16x16x32_bf16(alo[t], bh, acc1, 0, 0, 0);
            acc0 = __builtin_amdgcn_mfma_f32_16x16x32_bf16(ahi[t], bl, acc0, 0, 0, 0);
        }

        const int col = nt * 16 + mrow;
        float bias = bout[col];
        #pragma unroll
        for (int r = 0; r < 4; r++) {
            int node = nbase + kg * 4 + r;
            if (node < N_NODES)
                out[(size_t)node * D + col] =
                    nf[(size_t)node * D + col] + bias + acc0[r] + acc1[r];
        }
    }
}

// ---------------------------------------------------------------------------
// launch
// ---------------------------------------------------------------------------
extern "C" void kernel_launch(void* const* d_in, const int* in_sizes, int n_in,
                              void* d_out, int out_size, void* d_ws, size_t ws_size,
                              hipStream_t stream) {
    const float* nf    = (const float*)d_in[0];
    const float* dist  = (const float*)d_in[1];
    const float* path  = (const float*)d_in[2];
    const float* gamma = (const float*)d_in[3];
    const float* beta  = (const float*)d_in[4];
    const float* Wqkv  = (const float*)d_in[5];
    const float* bqkv  = (const float*)d_in[6];
    const float* Wout  = (const float*)d_in[7];
    const float* bout  = (const float*)d_in[8];
    const int*   src   = (const int*)d_in[9];
    const int*   dst   = (const int*)d_in[10];
    float* out = (float*)d_out;

    // workspace layout (all 16B-aligned chunks):
    //   kb fp32 N*128, agg fp32 N*128, dp fp32 E*8,
    //   qv bf16 N*256, ssrc int E, cnt/ptrs/row_start ints,
    //   bf16 hi/lo weights
    float* kb  = (float*)d_ws;                               // N*128
    float* agg = kb + (size_t)N_NODES * D;                   // N*128
    float* dp  = agg + (size_t)N_NODES * D;                  // E*8
    unsigned short* qvb = (unsigned short*)(dp + (size_t)N_EDGES * 8);  // N*256
    int* ssrc      = (int*)(qvb + (size_t)N_NODES * 256);    // E
    int* cnt       = ssrc + N_EDGES;                         // N
    int* ptrs      = cnt + N_NODES;                          // N
    int* row_start = ptrs + N_NODES;                         // N+1
    uintptr_t p = (uintptr_t)(row_start + N_NODES + 1);
    p = (p + 15) & ~(uintptr_t)15;
    unsigned short* wq_hi = (unsigned short*)p;              // 384*128
    unsigned short* wq_lo = wq_hi + 384 * 128;
    unsigned short* wo_hi = wq_lo + 384 * 128;               // 128*128
    unsigned short* wo_lo = wo_hi + 128 * 128;

    (void)in_sizes; (void)n_in; (void)out_size; (void)ws_size;

    hipLaunchKernelGGL(k_prep, dim3(192), dim3(256), 0, stream,
                       Wqkv, Wout, wq_hi, wq_lo, wo_hi, wo_lo);

    hipLaunchKernelGGL(k_zero, dim3((N_NODES + 255) / 256), dim3(256), 0, stream, cnt);
    hipLaunchKernelGGL(k_hist, dim3((N_EDGES + 255) / 256), dim3(256), 0, stream,
                       dst, cnt);
    hipLaunchKernelGGL(k_scan, dim3(1), dim3(SCAN_T), 0, stream,
                       cnt, row_start, ptrs);
    hipLaunchKernelGGL(k_fill, dim3((N_EDGES + 255) / 256), dim3(256), 0, stream,
                       src, dst, dist, path, ptrs, ssrc, dp);

    hipLaunchKernelGGL(k_ln_qkv, dim3((N_NODES + 63) / 64), dim3(256), 0, stream,
                       nf, gamma, beta, wq_hi, wq_lo, bqkv, qvb, kb);

    hipLaunchKernelGGL(k_gather, dim3((N_NODES + 3) / 4), dim3(256), 0, stream,
                       qvb, kb, dp, row_start, ssrc, agg);

    hipLaunchKernelGGL(k_out, dim3((N_NODES + 63) / 64), dim3(256), 0, stream,
                       agg, wo_hi, wo_lo, bout, nf, out);
}

// Round 10
// 304.063 us; speedup vs baseline: 1.9373x; 1.3923x over previous
//
#include <hip/hip_runtime.h>
#include <math.h>

#define N_NODES 50000
#define N_EDGES 800000
#define D 128
#define NH 8
#define EPS 1e-5f
#define QSCALE 0.08838834764831845f  // 128^-0.5

typedef __attribute__((ext_vector_type(8))) short short8;
typedef __attribute__((ext_vector_type(4))) float f32x4;

// bf16 round-to-nearest-even helpers (bit-pattern in ushort)
__device__ __forceinline__ unsigned short f2bf_rne(float f) {
    unsigned int u = __float_as_uint(f);
    u += 0x7fff + ((u >> 16) & 1);
    return (unsigned short)(u >> 16);
}
__device__ __forceinline__ float bf2f(unsigned short h) {
    return __uint_as_float(((unsigned int)h) << 16);
}
// unpack a uint holding [lo: bf16 a][hi: bf16 b] -> (a, b)
__device__ __forceinline__ float2 bfpair(unsigned int u) {
    return make_float2(__uint_as_float(u << 16),
                       __uint_as_float(u & 0xffff0000u));
}

// ---------------------------------------------------------------------------
// CSR build: zero -> histogram -> hierarchical scan (2 kernels) -> fill
// ---------------------------------------------------------------------------
__global__ void k_zero(int* __restrict__ cnt) {
    int i = blockIdx.x * blockDim.x + threadIdx.x;
    if (i < N_NODES) cnt[i] = 0;
}

__global__ void k_hist(const int* __restrict__ dst, int* __restrict__ cnt) {
    int e = blockIdx.x * blockDim.x + threadIdx.x;
    if (e < N_EDGES) atomicAdd(&cnt[dst[e]], 1);
}

#define SCB 1024
#define SCG ((N_NODES + SCB - 1) / SCB)   // 49 blocks (<= 64: one wave covers bsum)

// phase 1: per-block exclusive scan (shfl wave-scan + wave-sum combine).
// writes exclusive scan into row_start[gid], block total into bsum[blk].
__global__ void k_scan1(const int* __restrict__ cnt, int* __restrict__ row_start,
                        int* __restrict__ bsum) {
    __shared__ int wsum[16];
    const int tid = threadIdx.x, lane = tid & 63, wid = tid >> 6;
    const int gid = blockIdx.x * SCB + tid;
    const int v = (gid < N_NODES) ? cnt[gid] : 0;

    // inclusive wave scan (64 lanes, 6 shfl_up steps)
    int x = v;
    #pragma unroll
    for (int off = 1; off < 64; off <<= 1) {
        int t = __shfl_up(x, off);
        if (lane >= off) x += t;
    }
    if (lane == 63) wsum[wid] = x;
    __syncthreads();
    if (wid == 0) {
        int w = (lane < 16) ? wsum[lane] : 0;
        #pragma unroll
        for (int off = 1; off < 16; off <<= 1) {
            int t = __shfl_up(w, off);
            if (lane >= off) w += t;
        }
        if (lane < 16) wsum[lane] = w;    // inclusive wave-sum scan
    }
    __syncthreads();
    const int base = (wid > 0) ? wsum[wid - 1] : 0;
    const int incl = base + x;
    if (gid < N_NODES) row_start[gid] = incl - v;   // exclusive
    if (tid == SCB - 1) bsum[blockIdx.x] = incl;    // block total
}

// phase 2: add block offset (masked wave-reduce over 49 bsums), mirror to ptrs.
__global__ void k_scan2(const int* __restrict__ bsum, int* __restrict__ row_start,
                        int* __restrict__ ptrs) {
    __shared__ int boff_s;
    const int tid = threadIdx.x;
    if (tid < 64) {
        int v = (tid < blockIdx.x) ? bsum[tid] : 0;   // blockIdx.x <= 48 < 64
        #pragma unroll
        for (int off = 1; off < 64; off <<= 1) v += __shfl_xor(v, off);
        if (tid == 0) boff_s = v;
    }
    __syncthreads();
    const int gid = blockIdx.x * SCB + tid;
    if (gid < N_NODES) {
        int r = row_start[gid] + boff_s;
        row_start[gid] = r;
        ptrs[gid] = r;
    }
    if (gid == 0) row_start[N_NODES] = N_EDGES;   // exact: every dst < N_NODES
}

// fill: CSR src list + dist/path pre-gathered (summed) into CSR order.
__global__ void k_fill(const int* __restrict__ src, const int* __restrict__ dst,
                       const float* __restrict__ dist, const float* __restrict__ path,
                       int* __restrict__ ptrs, int* __restrict__ ssrc,
                       float* __restrict__ dp) {
    int e = blockIdx.x * blockDim.x + threadIdx.x;
    if (e < N_EDGES) {
        int d = dst[e];
        int pos = atomicAdd(&ptrs[d], 1);
        ssrc[pos] = src[e];
        #pragma unroll
        for (int h = 0; h < 8; h++)
            dp[(size_t)pos * 8 + h] = dist[(size_t)e * 8 + h] + path[(size_t)e * 8 + h];
    }
}

// ---------------------------------------------------------------------------
// K_prep: split W_qkv and W_out into bf16 hi/lo (for bf16x3 fp32-accurate MFMA)
// ---------------------------------------------------------------------------
__global__ void k_prep(const float* __restrict__ Wqkv, const float* __restrict__ Wout,
                       unsigned short* __restrict__ wq_hi, unsigned short* __restrict__ wq_lo,
                       unsigned short* __restrict__ wo_hi, unsigned short* __restrict__ wo_lo) {
    int i = blockIdx.x * blockDim.x + threadIdx.x;
    if (i < 384 * 128) {
        float w = Wqkv[i];
        unsigned short h = f2bf_rne(w);
        wq_hi[i] = h;
        wq_lo[i] = f2bf_rne(w - bf2f(h));
    }
    if (i < 128 * 128) {
        float w = Wout[i];
        unsigned short h = f2bf_rne(w);
        wo_hi[i] = h;
        wo_lo[i] = f2bf_rne(w - bf2f(h));
    }
}

// ---------------------------------------------------------------------------
// K1: LayerNorm + QKV projection via MFMA bf16x3 (fp32-equivalent).
// q and v are emitted as bf16 into the interleaved qv record:
//   ushort idx(n, pair p, j) : n*256 + p*4 + {0,1}=q pair, {2,3}=v pair
// so k_gather's lane l reads ONE uint2 (q2l,q2l+1,v2l,v2l+1) at n*512+8l bytes.
// k stays fp32 (read once per node, register-resident in k_gather).
// ---------------------------------------------------------------------------
__launch_bounds__(256)
__global__ void k_ln_qkv(const float* __restrict__ nf, const float* __restrict__ gamma,
                         const float* __restrict__ beta,
                         const unsigned short* __restrict__ w_hi,
                         const unsigned short* __restrict__ w_lo,
                         const float* __restrict__ bqkv,
                         unsigned short* __restrict__ qv, float* __restrict__ kb) {
    const int lane  = threadIdx.x & 63;
    const int wv    = threadIdx.x >> 6;
    const int nbase = blockIdx.x * 64 + wv * 16;
    const int mrow  = lane & 15;   // A-row (input node) AND B-col (W row)
    const int kg    = lane >> 4;   // k-group: k = t*32 + kg*8 + j

    int gn = nbase + mrow;
    if (gn >= N_NODES) gn = N_NODES - 1;           // clamp; stores are guarded
    const float* xrow = nf + (size_t)gn * D + kg * 8;
    float4 xa[4], xb[4];
    #pragma unroll
    for (int t = 0; t < 4; t++) {
        xa[t] = *(const float4*)(xrow + t * 32);
        xb[t] = *(const float4*)(xrow + t * 32 + 4);
    }

    // LN stats: reduce over the 4 lanes sharing this node (xor 16,32)
    float s = 0.f, ss = 0.f;
    #pragma unroll
    for (int t = 0; t < 4; t++) {
        s  += xa[t].x + xa[t].y + xa[t].z + xa[t].w
            + xb[t].x + xb[t].y + xb[t].z + xb[t].w;
        ss += xa[t].x * xa[t].x + xa[t].y * xa[t].y + xa[t].z * xa[t].z + xa[t].w * xa[t].w
            + xb[t].x * xb[t].x + xb[t].y * xb[t].y + xb[t].z * xb[t].z + xb[t].w * xb[t].w;
    }
    s += __shfl_xor(s, 16); ss += __shfl_xor(ss, 16);
    s += __shfl_xor(s, 32); ss += __shfl_xor(ss, 32);
    float mu   = s * (1.f / 128.f);
    float var  = ss * (1.f / 128.f) - mu * mu;
    float rstd = rsqrtf(var + EPS);

    // normalize + hi/lo split + pack A-fragments
    short8 ahi[4], alo[4];
    #pragma unroll
    for (int t = 0; t < 4; t++) {
        const float* gp = gamma + kg * 8 + t * 32;
        const float* bp = beta  + kg * 8 + t * 32;
        float4 g0 = *(const float4*)gp, g1 = *(const float4*)(gp + 4);
        float4 b0 = *(const float4*)bp, b1 = *(const float4*)(bp + 4);
        float xn[8];
        xn[0] = (xa[t].x - mu) * rstd * g0.x + b0.x;
        xn[1] = (xa[t].y - mu) * rstd * g0.y + b0.y;
        xn[2] = (xa[t].z - mu) * rstd * g0.z + b0.z;
        xn[3] = (xa[t].w - mu) * rstd * g0.w + b0.w;
        xn[4] = (xb[t].x - mu) * rstd * g1.x + b1.x;
        xn[5] = (xb[t].y - mu) * rstd * g1.y + b1.y;
        xn[6] = (xb[t].z - mu) * rstd * g1.z + b1.z;
        xn[7] = (xb[t].w - mu) * rstd * g1.w + b1.w;
        #pragma unroll
        for (int j = 0; j < 8; j++) {
            unsigned short h = f2bf_rne(xn[j]);
            ahi[t][j] = (short)h;
            alo[t][j] = (short)f2bf_rne(xn[j] - bf2f(h));
        }
    }

    // 24 N-tiles of 16 cols: D = Xhi*Whi + Xlo*Whi + Xhi*Wlo
    for (int nt = 0; nt < 24; nt++) {
        const unsigned short* wrh = w_hi + ((size_t)(nt * 16 + mrow)) * D + kg * 8;
        const unsigned short* wrl = w_lo + ((size_t)(nt * 16 + mrow)) * D + kg * 8;
        f32x4 acc0 = {0.f, 0.f, 0.f, 0.f};
        f32x4 acc1 = {0.f, 0.f, 0.f, 0.f};
        #pragma unroll
        for (int t = 0; t < 4; t++) {
            short8 bh = *(const short8*)(wrh + t * 32);
            short8 bl = *(const short8*)(wrl + t * 32);
            acc0 = __builtin_amdgcn_mfma_f32_16x16x32_bf16(ahi[t], bh, acc0, 0, 0, 0);
            acc1 = __builtin_amdgcn_mfma_f32_16x16x32_bf16(alo[t], bh, acc1, 0, 0, 0);
            acc0 = __builtin_amdgcn_mfma_f32_16x16x32_bf16(ahi[t], bl, acc0, 0, 0, 0);
        }

        const int col = nt * 16 + mrow;
        float bias = bqkv[col];
        #pragma unroll
        for (int r = 0; r < 4; r++) {
            int node = nbase + kg * 4 + r;   // D-row = (lane>>4)*4 + r
            if (node >= N_NODES) continue;
            float val = acc0[r] + acc1[r] + bias;
            if (col < 128) {
                // q, pre-scaled, bf16 into qv
                qv[(size_t)node * 256 + (col >> 1) * 4 + (col & 1)] =
                    f2bf_rne(val * QSCALE);
            } else if (col < 256) {
                kb[(size_t)node * D + (col - 128)] = val;
            } else {
                int cv = col - 256;
                qv[(size_t)node * 256 + (cv >> 1) * 4 + 2 + (cv & 1)] =
                    f2bf_rne(val);
            }
        }
    }
}

// ---------------------------------------------------------------------------
// K_gather: fused logits + online softmax + weighted-V aggregation.
// One wave per node. Lane l owns dims (2l,2l+1); head h = l>>3.
// Per edge: ONE uint2 gather (q-pair + v-pair, 512B/wave coalesced) +
// sequential dp read. No atomics; agg written exactly once.
// ---------------------------------------------------------------------------
__launch_bounds__(256, 4)
__global__ void k_gather(const unsigned short* __restrict__ qv,
                         const float* __restrict__ kb,
                         const float* __restrict__ dp,
                         const int* __restrict__ row_start,
                         const int* __restrict__ ssrc,
                         float* __restrict__ agg) {
    const int node = blockIdx.x * 4 + (threadIdx.x >> 6);
    if (node >= N_NODES) return;
    const int lane = threadIdx.x & 63;
    const int h = lane >> 3;
    const int beg = row_start[node], end = row_start[node + 1];

    const float2 kv = *(const float2*)(kb + (size_t)node * D + 2 * lane);
    float m = -INFINITY, sden = 0.f, ax = 0.f, ay = 0.f;

    int i = beg;
    for (; i + 2 <= end; i += 2) {          // 2-deep: batch the loads
        int sA = ssrc[i], sB = ssrc[i + 1];
        uint2 pa = *(const uint2*)(qv + (size_t)sA * 256 + lane * 4);
        uint2 pb = *(const uint2*)(qv + (size_t)sB * 256 + lane * 4);
        float dpA = dp[(size_t)i * 8 + h];
        float dpB = dp[(size_t)(i + 1) * 8 + h];
        float2 qA = bfpair(pa.x), vA = bfpair(pa.y);
        float2 qB = bfpair(pb.x), vB = bfpair(pb.y);
        float pA = qA.x * kv.x + qA.y * kv.y;
        float pB = qB.x * kv.x + qB.y * kv.y;
        pA += __shfl_xor(pA, 1); pA += __shfl_xor(pA, 2); pA += __shfl_xor(pA, 4);
        pB += __shfl_xor(pB, 1); pB += __shfl_xor(pB, 2); pB += __shfl_xor(pB, 4);
        pA += dpA; pB += dpB;

        float mn = fmaxf(m, pA);
        float c  = __expf(m - mn);
        float w  = __expf(pA - mn);
        sden = sden * c + w;
        ax = ax * c + w * vA.x;
        ay = ay * c + w * vA.y;
        m = mn;

        mn = fmaxf(m, pB);
        c  = __expf(m - mn);
        w  = __expf(pB - mn);
        sden = sden * c + w;
        ax = ax * c + w * vB.x;
        ay = ay * c + w * vB.y;
        m = mn;
    }
    if (i < end) {                           // tail edge
        int sA = ssrc[i];
        uint2 pa = *(const uint2*)(qv + (size_t)sA * 256 + lane * 4);
        float dpA = dp[(size_t)i * 8 + h];
        float2 qA = bfpair(pa.x), vA = bfpair(pa.y);
        float pA = qA.x * kv.x + qA.y * kv.y;
        pA += __shfl_xor(pA, 1); pA += __shfl_xor(pA, 2); pA += __shfl_xor(pA, 4);
        pA += dpA;
        float mn = fmaxf(m, pA);
        float c  = __expf(m - mn);
        float w  = __expf(pA - mn);
        sden = sden * c + w;
        ax = ax * c + w * vA.x;
        ay = ay * c + w * vA.y;
    }

    float2 r = make_float2(0.f, 0.f);
    if (end > beg) {
        float inv = 1.f / sden;
        r = make_float2(ax * inv, ay * inv);
    }
    *(float2*)(agg + (size_t)node * D + 2 * lane) = r;
}

// ---------------------------------------------------------------------------
// K5: out = node_feature + agg @ W_out.T + b_out, via MFMA bf16x3.
// ---------------------------------------------------------------------------
__launch_bounds__(256)
__global__ void k_out(const float* __restrict__ agg,
                      const unsigned short* __restrict__ w_hi,
                      const unsigned short* __restrict__ w_lo,
                      const float* __restrict__ bout, const float* __restrict__ nf,
                      float* __restrict__ out) {
    const int lane  = threadIdx.x & 63;
    const int wv    = threadIdx.x >> 6;
    const int nbase = blockIdx.x * 64 + wv * 16;
    const int mrow  = lane & 15;
    const int kg    = lane >> 4;

    int gn = nbase + mrow;
    if (gn >= N_NODES) gn = N_NODES - 1;
    const float* arow = agg + (size_t)gn * D + kg * 8;

    short8 ahi[4], alo[4];
    #pragma unroll
    for (int t = 0; t < 4; t++) {
        float4 x0 = *(const float4*)(arow + t * 32);
        float4 x1 = *(const float4*)(arow + t * 32 + 4);
        float xn[8] = {x0.x, x0.y, x0.z, x0.w, x1.x, x1.y, x1.z, x1.w};
        #pragma unroll
        for (int j = 0; j < 8; j++) {
            unsigned short h = f2bf_rne(xn[j]);
            ahi[t][j] = (short)h;
            alo[t][j] = (short)f2bf_rne(xn[j] - bf2f(h));
        }
    }

    for (int nt = 0; nt < 8; nt++) {
        const unsigned short* wrh = w_hi + ((size_t)(nt * 16 + mrow)) * D + kg * 8;
        const unsigned short* wrl = w_lo + ((size_t)(nt * 16 + mrow)) * D + kg * 8;
        f32x4 acc0 = {0.f, 0.f, 0.f, 0.f};
        f32x4 acc1 = {0.f, 0.f, 0.f, 0.f};
        #pragma unroll
        for (int t = 0; t < 4; t++) {
            short8 bh = *(const short8*)(wrh + t * 32);
            short8 bl = *(const short8*)(wrl + t * 32);
            acc0 = __builtin_amdgcn_mfma_f32_16x16x32_bf16(ahi[t], bh, acc0, 0, 0, 0);
            acc1 = __builtin_amdgcn_mfma_f32_16x16x32_bf16(alo[t], bh, acc1, 0, 0, 0);
            acc0 = __builtin_amdgcn_mfma_f32_16x16x32_bf16(ahi[t], bl, acc0, 0, 0, 0);
        }

        const int col = nt * 16 + mrow;
        float bias = bout[col];
        #pragma unroll
        for (int r = 0; r < 4; r++) {
            int node = nbase + kg * 4 + r;
            if (node < N_NODES)
                out[(size_t)node * D + col] =
                    nf[(size_t)node * D + col] + bias + acc0[r] + acc1[r];
        }
    }
}

// ---------------------------------------------------------------------------
// launch
// ---------------------------------------------------------------------------
extern "C" void kernel_launch(void* const* d_in, const int* in_sizes, int n_in,
                              void* d_out, int out_size, void* d_ws, size_t ws_size,
                              hipStream_t stream) {
    const float* nf    = (const float*)d_in[0];
    const float* dist  = (const float*)d_in[1];
    const float* path  = (const float*)d_in[2];
    const float* gamma = (const float*)d_in[3];
    const float* beta  = (const float*)d_in[4];
    const float* Wqkv  = (const float*)d_in[5];
    const float* bqkv  = (const float*)d_in[6];
    const float* Wout  = (const float*)d_in[7];
    const float* bout  = (const float*)d_in[8];
    const int*   src   = (const int*)d_in[9];
    const int*   dst   = (const int*)d_in[10];
    float* out = (float*)d_out;

    // workspace layout (all 16B-aligned chunks):
    //   kb fp32 N*128, agg fp32 N*128, dp fp32 E*8,
    //   qv bf16 N*256, ssrc int E, cnt/ptrs/row_start/bsum ints,
    //   bf16 hi/lo weights
    float* kb  = (float*)d_ws;                               // N*128
    float* agg = kb + (size_t)N_NODES * D;                   // N*128
    float* dp  = agg + (size_t)N_NODES * D;                  // E*8
    unsigned short* qvb = (unsigned short*)(dp + (size_t)N_EDGES * 8);  // N*256
    int* ssrc      = (int*)(qvb + (size_t)N_NODES * 256);    // E
    int* cnt       = ssrc + N_EDGES;                         // N
    int* ptrs      = cnt + N_NODES;                          // N
    int* row_start = ptrs + N_NODES;                         // N+1
    int* bsum      = row_start + N_NODES + 1;                // SCG (49), pad to 64
    uintptr_t p = (uintptr_t)(bsum + 64);
    p = (p + 15) & ~(uintptr_t)15;
    unsigned short* wq_hi = (unsigned short*)p;              // 384*128
    unsigned short* wq_lo = wq_hi + 384 * 128;
    unsigned short* wo_hi = wq_lo + 384 * 128;               // 128*128
    unsigned short* wo_lo = wo_hi + 128 * 128;

    (void)in_sizes; (void)n_in; (void)out_size; (void)ws_size;

    hipLaunchKernelGGL(k_prep, dim3(192), dim3(256), 0, stream,
                       Wqkv, Wout, wq_hi, wq_lo, wo_hi, wo_lo);

    hipLaunchKernelGGL(k_zero, dim3((N_NODES + 255) / 256), dim3(256), 0, stream, cnt);
    hipLaunchKernelGGL(k_hist, dim3((N_EDGES + 255) / 256), dim3(256), 0, stream,
                       dst, cnt);
    hipLaunchKernelGGL(k_scan1, dim3(SCG), dim3(SCB), 0, stream,
                       cnt, row_start, bsum);
    hipLaunchKernelGGL(k_scan2, dim3(SCG), dim3(SCB), 0, stream,
                       bsum, row_start, ptrs);
    hipLaunchKernelGGL(k_fill, dim3((N_EDGES + 255) / 256), dim3(256), 0, stream,
                       src, dst, dist, path, ptrs, ssrc, dp);

    hipLaunchKernelGGL(k_ln_qkv, dim3((N_NODES + 63) / 64), dim3(256), 0, stream,
                       nf, gamma, beta, wq_hi, wq_lo, bqkv, qvb, kb);

    hipLaunchKernelGGL(k_gather, dim3((N_NODES + 3) / 4), dim3(256), 0, stream,
                       qvb, kb, dp, row_start, ssrc, agg);

    hipLaunchKernelGGL(k_out, dim3((N_NODES + 63) / 64), dim3(256), 0, stream,
                       agg, wo_hi, wo_lo, bout, nf, out);
}